// Round 2
// baseline (607.854 us; speedup 1.0000x reference)
//
#include <hip/hip_runtime.h>
#include <hip/hip_bf16.h>

#define D_MODEL 256
#define SEQ     1024
#define NROWS   8192      // 8 batches * 1024
#define HD      32

// -------- 1. build f[row][c] = input(+transpose) + 0.1*pos --------
__global__ __launch_bounds__(256) void build_f_kernel(
    const float* __restrict__ x, const float* __restrict__ y, float* __restrict__ f)
{
  int idx = blockIdx.x * 256 + threadIdx.x;     // over 8192*256
  int c   = idx & 255;
  int row = idx >> 8;
  int s   = row & 1023;
  int b   = row >> 10;
  int h   = s >> 5, w = s & 31;
  int cc  = c;
  const float sc = 6.28318530717958647692f / (32.0f + 1e-6f);
  float e;
  if (cc < 128) { e = (float)(h + 1) * sc; }
  else          { e = (float)(w + 1) * sc; cc -= 128; }
  int j = cc >> 1;
  float t   = powf(10000.0f, (float)j * (1.0f / 64.0f));
  float arg = e / t;
  float pv  = (cc & 1) ? cosf(arg) : sinf(arg);
  const float* src = (b < 4) ? x : y;
  int bb = b & 3;
  float xv = src[((size_t)((bb << 8) + c) << 10) + s];
  f[idx] = xv + 0.1f * pv;
}

// -------- 2. generic NT GEMM: C[M][N] = A[M][K] * B[N][K]^T + bias --------
__global__ __launch_bounds__(256) void gemm_nt_kernel(
    const float* __restrict__ A, const float* __restrict__ B,
    const float* __restrict__ bias, float* __restrict__ C,
    int M, int N, int K, int relu)
{
  __shared__ float As[16][64];
  __shared__ float Bs[16][64];
  int tid = threadIdx.x;
  int tx = tid & 15, ty = tid >> 4;
  int m0 = blockIdx.y * 64, n0 = blockIdx.x * 64;
  int lm = tid >> 2, lk4 = (tid & 3) << 2;
  float acc[4][4] = {};
  for (int k0 = 0; k0 < K; k0 += 16) {
    float4 av = *(const float4*)&A[(size_t)(m0 + lm) * K + k0 + lk4];
    float4 bv = *(const float4*)&B[(size_t)(n0 + lm) * K + k0 + lk4];
    As[lk4 + 0][lm] = av.x; As[lk4 + 1][lm] = av.y;
    As[lk4 + 2][lm] = av.z; As[lk4 + 3][lm] = av.w;
    Bs[lk4 + 0][lm] = bv.x; Bs[lk4 + 1][lm] = bv.y;
    Bs[lk4 + 2][lm] = bv.z; Bs[lk4 + 3][lm] = bv.w;
    __syncthreads();
    #pragma unroll
    for (int kk = 0; kk < 16; ++kk) {
      float a[4], b4[4];
      #pragma unroll
      for (int i = 0; i < 4; ++i) a[i]  = As[kk][ty * 4 + i];
      #pragma unroll
      for (int j2 = 0; j2 < 4; ++j2) b4[j2] = Bs[kk][tx * 4 + j2];
      #pragma unroll
      for (int i = 0; i < 4; ++i)
        #pragma unroll
        for (int j2 = 0; j2 < 4; ++j2)
          acc[i][j2] += a[i] * b4[j2];
    }
    __syncthreads();
  }
  #pragma unroll
  for (int j2 = 0; j2 < 4; ++j2) {
    int n = n0 + tx * 4 + j2;
    float bb = bias[n];
    #pragma unroll
    for (int i = 0; i < 4; ++i) {
      float v = acc[i][j2] + bb;
      if (relu) v = fmaxf(v, 0.0f);
      C[(size_t)(m0 + ty * 4 + i) * N + n] = v;
    }
  }
}

// -------- 3. attention: 1 thread = 1 q row, K/V tiles in LDS, online softmax --------
__global__ __launch_bounds__(256) void attn_kernel(
    const float* __restrict__ qkv, float* __restrict__ att)
{
  __shared__ float Kt[64][HD];
  __shared__ float Vt[64][HD];
  int t  = threadIdx.x;
  int qc = blockIdx.x, hh = blockIdx.y, b = blockIdx.z;
  int row = b * SEQ + qc * 256 + t;
  const float* qrow = qkv + (size_t)row * 768 + hh * HD;
  float q[HD];
  #pragma unroll
  for (int d = 0; d < HD; ++d) q[d] = qrow[d];
  float m = -1e30f, l = 0.0f;
  float o[HD] = {};
  for (int kt = 0; kt < SEQ; kt += 64) {
    __syncthreads();
    for (int e = t; e < 64 * HD; e += 256) {
      int r = e >> 5, d = e & 31;
      const float* base = qkv + (size_t)(b * SEQ + kt + r) * 768 + hh * HD + d;
      Kt[r][d] = base[256];
      Vt[r][d] = base[512];
    }
    __syncthreads();
    for (int kk = 0; kk < 64; ++kk) {
      float s = 0.0f;
      #pragma unroll
      for (int d = 0; d < HD; ++d) s += q[d] * Kt[kk][d];
      s *= 0.17677669529663688110f;   // 1/sqrt(32)
      if (s > m) {
        float corr = __expf(m - s);
        l *= corr;
        #pragma unroll
        for (int d = 0; d < HD; ++d) o[d] *= corr;
        m = s;
      }
      float p = __expf(s - m);
      l += p;
      #pragma unroll
      for (int d = 0; d < HD; ++d) o[d] += p * Vt[kk][d];
    }
  }
  float inv = 1.0f / l;
  float* orow = att + (size_t)row * D_MODEL + hh * HD;
  #pragma unroll
  for (int d = 0; d < HD; ++d) orow[d] = o[d] * inv;
}

// -------- 4. residual + layernorm (fp32 out) --------
__global__ __launch_bounds__(256) void add_ln_kernel(
    const float* __restrict__ A, const float* __restrict__ R,
    const float* __restrict__ g, const float* __restrict__ bta,
    float* __restrict__ out)
{
  __shared__ float sm[8];
  int row = blockIdx.x, c = threadIdx.x;
  size_t idx = (size_t)row * D_MODEL + c;
  float v = A[idx] + R[idx];
  float s = v;
  #pragma unroll
  for (int off = 32; off >= 1; off >>= 1) s += __shfl_down(s, off);
  if ((c & 63) == 0) sm[c >> 6] = s;
  __syncthreads();
  if (c == 0) sm[0] = (sm[0] + sm[1] + sm[2] + sm[3]) * (1.0f / 256.0f);
  __syncthreads();
  float mu = sm[0];
  float d  = v - mu;
  float s2 = d * d;
  #pragma unroll
  for (int off = 32; off >= 1; off >>= 1) s2 += __shfl_down(s2, off);
  if ((c & 63) == 0) sm[4 + (c >> 6)] = s2;
  __syncthreads();
  if (c == 0) sm[1] = rsqrtf((sm[4] + sm[5] + sm[6] + sm[7]) * (1.0f / 256.0f) + 1e-5f);
  __syncthreads();
  float rstd = sm[1];
  out[idx] = d * rstd * g[c] + bta[c];
}

// -------- 5. residual + layernorm + transpose-out (fp32) --------
__global__ __launch_bounds__(256) void add_ln_out_kernel(
    const float* __restrict__ A, const float* __restrict__ R,
    const float* __restrict__ g, const float* __restrict__ bta,
    float* __restrict__ out)
{
  __shared__ float sm[8];
  int row = blockIdx.x, c = threadIdx.x;
  size_t idx = (size_t)row * D_MODEL + c;
  float v = A[idx] + R[idx];
  float s = v;
  #pragma unroll
  for (int off = 32; off >= 1; off >>= 1) s += __shfl_down(s, off);
  if ((c & 63) == 0) sm[c >> 6] = s;
  __syncthreads();
  if (c == 0) sm[0] = (sm[0] + sm[1] + sm[2] + sm[3]) * (1.0f / 256.0f);
  __syncthreads();
  float mu = sm[0];
  float d  = v - mu;
  float s2 = d * d;
  #pragma unroll
  for (int off = 32; off >= 1; off >>= 1) s2 += __shfl_down(s2, off);
  if ((c & 63) == 0) sm[4 + (c >> 6)] = s2;
  __syncthreads();
  if (c == 0) sm[1] = rsqrtf((sm[4] + sm[5] + sm[6] + sm[7]) * (1.0f / 256.0f) + 1e-5f);
  __syncthreads();
  float rstd = sm[1];
  float res = d * rstd * g[c] + bta[c];
  int b = row >> 10, sq = row & 1023;
  size_t dst;
  if (b < 4) dst = ((size_t)((b << 8) + c) << 10) + sq;
  else       dst = (size_t)1048576 + ((size_t)(((b - 4) << 8) + c) << 10) + sq;
  out[dst] = res;
}

extern "C" void kernel_launch(void* const* d_in, const int* in_sizes, int n_in,
                              void* d_out, int out_size, void* d_ws, size_t ws_size,
                              hipStream_t stream)
{
  const float* x    = (const float*)d_in[0];
  const float* y    = (const float*)d_in[1];
  // d_in[2] = nhead (int scalar, == 8, unused)
  const float* Wqkv = (const float*)d_in[3];
  const float* bqkv = (const float*)d_in[4];
  const float* Wo   = (const float*)d_in[5];
  const float* bo   = (const float*)d_in[6];
  const float* W1   = (const float*)d_in[7];
  const float* b1   = (const float*)d_in[8];
  const float* W2   = (const float*)d_in[9];
  const float* b2   = (const float*)d_in[10];
  const float* g1   = (const float*)d_in[11];
  const float* be1  = (const float*)d_in[12];
  const float* g2   = (const float*)d_in[13];
  const float* be2  = (const float*)d_in[14];

  float* ws   = (float*)d_ws;
  float* f    = ws;               // 2,097,152 f32
  float* qkv  = ws +  2097152;    // 6,291,456
  float* att  = ws +  8388608;    // 2,097,152
  float* tmp  = ws + 10485760;    // 2,097,152
  float* f1   = ws + 12582912;    // 2,097,152
  float* hbuf = ws;               // reuse [f|qkv] region: 8,388,608
  float* tmp2 = ws +  8388608;    // reuse att region

  build_f_kernel<<<8192, 256, 0, stream>>>(x, y, f);
  gemm_nt_kernel<<<dim3(12, 128), 256, 0, stream>>>(f,    Wqkv, bqkv, qkv,  8192,  768,  256, 0);
  attn_kernel   <<<dim3(4, 8, 8), 256, 0, stream>>>(qkv, att);
  gemm_nt_kernel<<<dim3(4, 128),  256, 0, stream>>>(att,  Wo,   bo,   tmp,  8192,  256,  256, 0);
  add_ln_kernel <<<8192, 256, 0, stream>>>(tmp, f, g1, be1, f1);
  gemm_nt_kernel<<<dim3(16, 128), 256, 0, stream>>>(f1,   W1,   b1,   hbuf, 8192, 1024,  256, 1);
  gemm_nt_kernel<<<dim3(4, 128),  256, 0, stream>>>(hbuf, W2,   b2,   tmp2, 8192,  256, 1024, 0);
  add_ln_out_kernel<<<8192, 256, 0, stream>>>(tmp2, f1, g2, be2, (float*)d_out);
}

// Round 3
// 148.390 us; speedup vs baseline: 4.0963x; 4.0963x over previous
//
#include <hip/hip_runtime.h>

typedef __attribute__((ext_vector_type(8))) short bf16x8;
typedef __attribute__((ext_vector_type(4))) float f32x4;

#define D_MODEL 256
#define SEQ     1024
#define NROWS   8192

__device__ __forceinline__ ushort f2bf(float f) {
  unsigned u = __float_as_uint(f);
  unsigned r = (u + 0x7FFFu + ((u >> 16) & 1u)) >> 16;
  return (ushort)r;
}
__device__ __forceinline__ float bf2f(ushort b) {
  return __uint_as_float(((unsigned)b) << 16);
}

// -------- 0. convert weights fp32 -> bf16 --------
__global__ __launch_bounds__(256) void conv_w_kernel(
    const float* __restrict__ a, const float* __restrict__ b,
    const float* __restrict__ c, const float* __restrict__ d,
    ushort* __restrict__ oa, ushort* __restrict__ ob,
    ushort* __restrict__ oc, ushort* __restrict__ od)
{
  int i = blockIdx.x * 256 + threadIdx.x;   // grid covers 262144
  if (i < 196608) oa[i] = f2bf(a[i]);
  if (i <  65536) ob[i] = f2bf(b[i]);
  oc[i] = f2bf(c[i]);
  od[i] = f2bf(d[i]);
}

// -------- 1. build f[row][c] = input(+transpose) + 0.1*pos  (f32 + bf16) --------
__global__ __launch_bounds__(256) void build_f_kernel(
    const float* __restrict__ x, const float* __restrict__ y,
    float* __restrict__ f, ushort* __restrict__ fb)
{
  int idx = blockIdx.x * 256 + threadIdx.x;
  int c   = idx & 255;
  int row = idx >> 8;
  int s   = row & 1023;
  int b   = row >> 10;
  int h   = s >> 5, w = s & 31;
  int cc  = c;
  const float sc = 6.28318530717958647692f / (32.0f + 1e-6f);
  float e;
  if (cc < 128) { e = (float)(h + 1) * sc; }
  else          { e = (float)(w + 1) * sc; cc -= 128; }
  int j = cc >> 1;
  float t   = powf(10000.0f, (float)j * (1.0f / 64.0f));
  float arg = e / t;
  float pv  = (cc & 1) ? cosf(arg) : sinf(arg);
  const float* src = (b < 4) ? x : y;
  int bb = b & 3;
  float xv = src[((size_t)((bb << 8) + c) << 10) + s];
  float v = xv + 0.1f * pv;
  f[idx]  = v;
  fb[idx] = f2bf(v);
}

// -------- 2. MFMA GEMM: C[M][N] = A[M][K](bf16) * B[N][K]^T(bf16) + bias --------
// 128x128 tile, BK=64, 4 waves (2x2 of 64x64), XOR-swizzled LDS.
template<int OUT_BF16, int RELU>
__global__ __launch_bounds__(256) void gemm_mfma_kernel(
    const ushort* __restrict__ A, const ushort* __restrict__ B,
    const float* __restrict__ bias, void* __restrict__ Cout,
    int M, int N, int K)
{
  __shared__ ushort Asw[128 * 64];
  __shared__ ushort Bsw[128 * 64];
  const int tid  = threadIdx.x;
  const int lane = tid & 63;
  const int w    = tid >> 6;
  const int m0 = blockIdx.y * 128, n0 = blockIdx.x * 128;
  const int wm0 = (w & 1) * 64, wn0 = (w >> 1) * 64;
  const int l15 = lane & 15, g = lane >> 4;

  f32x4 acc[4][4];
  #pragma unroll
  for (int i = 0; i < 4; ++i)
    #pragma unroll
    for (int j = 0; j < 4; ++j)
      acc[i][j] = (f32x4){0.f, 0.f, 0.f, 0.f};

  for (int kt = 0; kt < K; kt += 64) {
    __syncthreads();
    #pragma unroll
    for (int j = 0; j < 4; ++j) {
      int chunk = j * 256 + tid;        // 0..1023
      int row = chunk >> 3, slot = chunk & 7;
      int sw  = slot ^ (row & 7);
      uint4 va = *(const uint4*)&A[(size_t)(m0 + row) * K + kt + slot * 8];
      *(uint4*)&Asw[row * 64 + sw * 8] = va;
      uint4 vb = *(const uint4*)&B[(size_t)(n0 + row) * K + kt + slot * 8];
      *(uint4*)&Bsw[row * 64 + sw * 8] = vb;
    }
    __syncthreads();
    #pragma unroll
    for (int ks = 0; ks < 2; ++ks) {
      bf16x8 af[4], bfr[4];
      #pragma unroll
      for (int i = 0; i < 4; ++i) {
        int ra = wm0 + i * 16 + l15;
        int sa = (ks * 4 + g) ^ (ra & 7);
        af[i]  = *(const bf16x8*)&Asw[ra * 64 + sa * 8];
        int rb = wn0 + i * 16 + l15;
        int sb = (ks * 4 + g) ^ (rb & 7);
        bfr[i] = *(const bf16x8*)&Bsw[rb * 64 + sb * 8];
      }
      #pragma unroll
      for (int mi = 0; mi < 4; ++mi)
        #pragma unroll
        for (int ni = 0; ni < 4; ++ni)
          acc[mi][ni] = __builtin_amdgcn_mfma_f32_16x16x32_bf16(
              af[mi], bfr[ni], acc[mi][ni], 0, 0, 0);
    }
  }

  float bv[4];
  #pragma unroll
  for (int ni = 0; ni < 4; ++ni) bv[ni] = bias[n0 + wn0 + ni * 16 + l15];
  #pragma unroll
  for (int mi = 0; mi < 4; ++mi)
    #pragma unroll
    for (int ni = 0; ni < 4; ++ni)
      #pragma unroll
      for (int r = 0; r < 4; ++r) {
        float v = acc[mi][ni][r] + bv[ni];
        if (RELU) v = fmaxf(v, 0.0f);
        size_t m = m0 + wm0 + mi * 16 + g * 4 + r;
        size_t n = n0 + wn0 + ni * 16 + l15;
        if (OUT_BF16) ((ushort*)Cout)[m * N + n] = f2bf(v);
        else          ((float*) Cout)[m * N + n] = v;
      }
}

// -------- 3. MFMA flash attention --------
// grid (8 qtiles, 8 heads, 8 batch); 4 waves x 32 q-rows; KV tiles of 64.
__global__ __launch_bounds__(256) void attn_mfma_kernel(
    const ushort* __restrict__ qkv, ushort* __restrict__ attout)
{
  __shared__ ushort Qs[128 * 32];
  __shared__ ushort Ks[64 * 32];
  __shared__ ushort Vt[32 * 64];        // swizzled [d][t]
  __shared__ ushort Ps[4][32 * 64];     // swizzled per-wave [q][t]
  const int tid  = threadIdx.x;
  const int lane = tid & 63;
  const int w    = tid >> 6;
  const int l15 = lane & 15, g = lane >> 4;
  const int qt = blockIdx.x, h = blockIdx.y, b = blockIdx.z;
  const size_t base = (size_t)b * SEQ * 768;
  const int q0 = qt * 128;
  const int wq0 = w * 32;
  const float sc = 0.25507964954389985f;   // (1/sqrt(32)) * log2(e)

  // stage Q (once)
  #pragma unroll
  for (int j = 0; j < 2; ++j) {
    int chunk = j * 256 + tid;            // 0..511
    int row = chunk >> 2, quarter = chunk & 3;
    uint4 v = *(const uint4*)&qkv[base + (size_t)(q0 + row) * 768 + h * 32 + quarter * 8];
    *(uint4*)&Qs[row * 32 + quarter * 8] = v;
  }

  float m_[2] = {-1e30f, -1e30f};
  float l_[2] = {0.f, 0.f};
  f32x4 o[2][2];
  #pragma unroll
  for (int a = 0; a < 2; ++a)
    #pragma unroll
    for (int d = 0; d < 2; ++d) o[a][d] = (f32x4){0.f, 0.f, 0.f, 0.f};
  const f32x4 zero = (f32x4){0.f, 0.f, 0.f, 0.f};

  for (int kv = 0; kv < SEQ; kv += 64) {
    __syncthreads();
    {   // stage K tile: 1 chunk/thread
      int row = tid >> 2, quarter = tid & 3;
      uint4 v = *(const uint4*)&qkv[base + (size_t)(kv + row) * 768 + 256 + h * 32 + quarter * 8];
      *(uint4*)&Ks[row * 32 + quarter * 8] = v;
    }
    {   // stage V^T (swizzled): d = tid&31, t-run of 8
      int d = tid & 31, t0 = (tid >> 5) * 8;
      union { ushort u[8]; uint4 v; } pk;
      #pragma unroll
      for (int i = 0; i < 8; ++i)
        pk.u[i] = qkv[base + (size_t)(kv + t0 + i) * 768 + 512 + h * 32 + d];
      int sw = (t0 >> 3) ^ (d & 7);
      *(uint4*)&Vt[d * 64 + sw * 8] = pk.v;
    }
    __syncthreads();

    // S^T = K . Q^T : lane owns q = wq0 + qi*16 + l15, t = kv + ti*16 + g*4 + r
    bf16x8 kf[4], qf[2];
    #pragma unroll
    for (int ti = 0; ti < 4; ++ti)
      kf[ti] = *(const bf16x8*)&Ks[(ti * 16 + l15) * 32 + g * 8];
    #pragma unroll
    for (int qi = 0; qi < 2; ++qi)
      qf[qi] = *(const bf16x8*)&Qs[(wq0 + qi * 16 + l15) * 32 + g * 8];
    f32x4 s[4][2];
    #pragma unroll
    for (int ti = 0; ti < 4; ++ti)
      #pragma unroll
      for (int qi = 0; qi < 2; ++qi)
        s[ti][qi] = __builtin_amdgcn_mfma_f32_16x16x32_bf16(kf[ti], qf[qi], zero, 0, 0, 0);

    // online softmax per qi
    #pragma unroll
    for (int qi = 0; qi < 2; ++qi) {
      float mx = -1e30f;
      #pragma unroll
      for (int ti = 0; ti < 4; ++ti)
        #pragma unroll
        for (int r = 0; r < 4; ++r) mx = fmaxf(mx, s[ti][qi][r]);
      mx = fmaxf(mx, __shfl_xor(mx, 16));
      mx = fmaxf(mx, __shfl_xor(mx, 32));
      float mnew = fmaxf(m_[qi], mx);
      float corr = exp2f((m_[qi] - mnew) * sc);
      float rs = 0.f;
      int q = qi * 16 + l15;
      #pragma unroll
      for (int ti = 0; ti < 4; ++ti) {
        ushort pb[4];
        #pragma unroll
        for (int r = 0; r < 4; ++r) {
          float p = exp2f((s[ti][qi][r] - mnew) * sc);
          rs += p;
          pb[r] = f2bf(p);
        }
        int tb   = ti * 16 + g * 4;
        int slot = tb >> 3;
        int sw   = slot ^ (q & 7);
        uint2 val;
        val.x = (unsigned)pb[0] | ((unsigned)pb[1] << 16);
        val.y = (unsigned)pb[2] | ((unsigned)pb[3] << 16);
        *(uint2*)&Ps[w][q * 64 + sw * 8 + (g & 1) * 4] = val;
      }
      rs += __shfl_xor(rs, 16);
      rs += __shfl_xor(rs, 32);
      l_[qi] = l_[qi] * corr + rs;
      m_[qi] = mnew;
      #pragma unroll
      for (int r = 0; r < 4; ++r) {
        float cr = __shfl(corr, g * 4 + r);
        o[qi][0][r] *= cr;
        o[qi][1][r] *= cr;
      }
    }

    // PV: O += P . V
    bf16x8 pa[2][2], vb[2][2];
    #pragma unroll
    for (int mi = 0; mi < 2; ++mi)
      #pragma unroll
      for (int ks = 0; ks < 2; ++ks) {
        int q  = mi * 16 + l15;
        int sw = (ks * 4 + g) ^ (q & 7);
        pa[mi][ks] = *(const bf16x8*)&Ps[w][q * 64 + sw * 8];
      }
    #pragma unroll
    for (int ks = 0; ks < 2; ++ks)
      #pragma unroll
      for (int di = 0; di < 2; ++di) {
        int d  = di * 16 + l15;
        int sw = (ks * 4 + g) ^ (d & 7);
        vb[ks][di] = *(const bf16x8*)&Vt[d * 64 + sw * 8];
      }
    #pragma unroll
    for (int mi = 0; mi < 2; ++mi)
      #pragma unroll
      for (int di = 0; di < 2; ++di)
        #pragma unroll
        for (int ks = 0; ks < 2; ++ks)
          o[mi][di] = __builtin_amdgcn_mfma_f32_16x16x32_bf16(
              pa[mi][ks], vb[ks][di], o[mi][di], 0, 0, 0);
  }

  // final normalize + store bf16 [8192][256]
  #pragma unroll
  for (int qi = 0; qi < 2; ++qi) {
    #pragma unroll
    for (int r = 0; r < 4; ++r) {
      float lr  = __shfl(l_[qi], g * 4 + r);
      float inv = 1.0f / lr;
      size_t row = (size_t)b * SEQ + q0 + wq0 + qi * 16 + g * 4 + r;
      #pragma unroll
      for (int di = 0; di < 2; ++di) {
        float v = o[qi][di][r] * inv;
        attout[row * D_MODEL + h * 32 + di * 16 + l15] = f2bf(v);
      }
    }
  }
}

// -------- 4. residual + layernorm (f32 + bf16 out) --------
__global__ __launch_bounds__(256) void add_ln_dual_kernel(
    const float* __restrict__ A, const float* __restrict__ R,
    const float* __restrict__ g, const float* __restrict__ bta,
    float* __restrict__ out, ushort* __restrict__ outb)
{
  __shared__ float sm[8];
  int row = blockIdx.x, c = threadIdx.x;
  size_t idx = (size_t)row * D_MODEL + c;
  float v = A[idx] + R[idx];
  float s = v;
  #pragma unroll
  for (int off = 32; off >= 1; off >>= 1) s += __shfl_down(s, off);
  if ((c & 63) == 0) sm[c >> 6] = s;
  __syncthreads();
  if (c == 0) sm[0] = (sm[0] + sm[1] + sm[2] + sm[3]) * (1.0f / 256.0f);
  __syncthreads();
  float mu = sm[0];
  float d  = v - mu;
  float s2 = d * d;
  #pragma unroll
  for (int off = 32; off >= 1; off >>= 1) s2 += __shfl_down(s2, off);
  if ((c & 63) == 0) sm[4 + (c >> 6)] = s2;
  __syncthreads();
  if (c == 0) sm[1] = rsqrtf((sm[4] + sm[5] + sm[6] + sm[7]) * (1.0f / 256.0f) + 1e-5f);
  __syncthreads();
  float res = d * sm[1] * g[c] + bta[c];
  out[idx]  = res;
  outb[idx] = f2bf(res);
}

// -------- 5. residual + layernorm + transpose-out (f32) --------
__global__ __launch_bounds__(256) void add_ln_out_kernel(
    const float* __restrict__ A, const float* __restrict__ R,
    const float* __restrict__ g, const float* __restrict__ bta,
    float* __restrict__ out)
{
  __shared__ float sm[8];
  int row = blockIdx.x, c = threadIdx.x;
  size_t idx = (size_t)row * D_MODEL + c;
  float v = A[idx] + R[idx];
  float s = v;
  #pragma unroll
  for (int off = 32; off >= 1; off >>= 1) s += __shfl_down(s, off);
  if ((c & 63) == 0) sm[c >> 6] = s;
  __syncthreads();
  if (c == 0) sm[0] = (sm[0] + sm[1] + sm[2] + sm[3]) * (1.0f / 256.0f);
  __syncthreads();
  float mu = sm[0];
  float d  = v - mu;
  float s2 = d * d;
  #pragma unroll
  for (int off = 32; off >= 1; off >>= 1) s2 += __shfl_down(s2, off);
  if ((c & 63) == 0) sm[4 + (c >> 6)] = s2;
  __syncthreads();
  if (c == 0) sm[1] = rsqrtf((sm[4] + sm[5] + sm[6] + sm[7]) * (1.0f / 256.0f) + 1e-5f);
  __syncthreads();
  float res = d * sm[1] * g[c] + bta[c];
  int b = row >> 10, sq = row & 1023;
  size_t dst;
  if (b < 4) dst = ((size_t)((b << 8) + c) << 10) + sq;
  else       dst = (size_t)1048576 + ((size_t)(((b - 4) << 8) + c) << 10) + sq;
  out[dst] = res;
}

extern "C" void kernel_launch(void* const* d_in, const int* in_sizes, int n_in,
                              void* d_out, int out_size, void* d_ws, size_t ws_size,
                              hipStream_t stream)
{
  const float* x    = (const float*)d_in[0];
  const float* y    = (const float*)d_in[1];
  const float* Wqkv = (const float*)d_in[3];
  const float* bqkv = (const float*)d_in[4];
  const float* Wo   = (const float*)d_in[5];
  const float* bo   = (const float*)d_in[6];
  const float* W1   = (const float*)d_in[7];
  const float* b1   = (const float*)d_in[8];
  const float* W2   = (const float*)d_in[9];
  const float* b2   = (const float*)d_in[10];
  const float* g1   = (const float*)d_in[11];
  const float* be1  = (const float*)d_in[12];
  const float* g2   = (const float*)d_in[13];
  const float* be2  = (const float*)d_in[14];

  float* ws = (float*)d_ws;
  float*  f      = ws;                           // [0, 2M) f32
  ushort* f_bf   = (ushort*)(ws + 2097152);      // [2M, 3M)
  ushort* qkv_bf = (ushort*)(ws + 3145728);      // [3M, 6M)
  ushort* att_bf = (ushort*)(ws + 6291456);      // [6M, 7M)
  float*  tmp    = ws + 7340032;                 // [7M, 9M)
  float*  f1     = ws + 9437184;                 // [9M, 11M)
  ushort* f1_bf  = (ushort*)(ws + 11534336);     // [11M, 12M)
  ushort* h_bf   = (ushort*)(ws + 2097152);      // reuse [2M, 6M)
  float*  tmp2   = ws + 6291456;                 // reuse [6M, 8M)
  ushort* wq_bf  = (ushort*)(ws + 12582912);
  ushort* wo_bf  = wq_bf + 196608;
  ushort* w1_bf  = wo_bf + 65536;
  ushort* w2_bf  = w1_bf + 262144;

  conv_w_kernel<<<1024, 256, 0, stream>>>(Wqkv, Wo, W1, W2, wq_bf, wo_bf, w1_bf, w2_bf);
  build_f_kernel<<<8192, 256, 0, stream>>>(x, y, f, f_bf);
  gemm_mfma_kernel<1, 0><<<dim3(6, 64), 256, 0, stream>>>(f_bf, wq_bf, bqkv, qkv_bf, NROWS, 768, 256);
  attn_mfma_kernel<<<dim3(8, 8, 8), 256, 0, stream>>>(qkv_bf, att_bf);
  gemm_mfma_kernel<0, 0><<<dim3(2, 64), 256, 0, stream>>>(att_bf, wo_bf, bo, tmp, NROWS, 256, 256);
  add_ln_dual_kernel<<<8192, 256, 0, stream>>>(tmp, f, g1, be1, f1, f1_bf);
  gemm_mfma_kernel<1, 1><<<dim3(8, 64), 256, 0, stream>>>(f1_bf, w1_bf, b1, h_bf, NROWS, 1024, 256);
  gemm_mfma_kernel<0, 0><<<dim3(2, 64), 256, 0, stream>>>(h_bf, w2_bf, b2, tmp2, NROWS, 256, 1024);
  add_ln_out_kernel<<<8192, 256, 0, stream>>>(tmp2, f1, g2, be2, (float*)d_out);
}

// Round 4
// 137.173 us; speedup vs baseline: 4.4313x; 1.0818x over previous
//
#include <hip/hip_runtime.h>

typedef __attribute__((ext_vector_type(8))) short bf16x8;
typedef __attribute__((ext_vector_type(4))) float f32x4;

#define D_MODEL 256
#define SEQ     1024
#define NROWS   8192

__device__ __forceinline__ ushort f2bf(float f) {
  unsigned u = __float_as_uint(f);
  unsigned r = (u + 0x7FFFu + ((u >> 16) & 1u)) >> 16;
  return (ushort)r;
}

// async global->LDS, 16B per lane; dst = wave-uniform base + lane*16
__device__ __forceinline__ void gld_lds16(const void* g, void* l) {
  __builtin_amdgcn_global_load_lds(
      (const __attribute__((address_space(1))) void*)g,
      (__attribute__((address_space(3))) void*)l, 16, 0, 0);
}

// XOR-swizzle of 8-element blocks within 64-col groups
__device__ __forceinline__ int swz(int col, int row7) {
  return (col & ~63) | ((((col >> 3) & 7) ^ row7) << 3) | (col & 7);
}

// -------- 0. weights fp32 -> bf16, pre-swizzled --------
__global__ __launch_bounds__(256) void conv_w_kernel(
    const float* __restrict__ a, const float* __restrict__ b,
    const float* __restrict__ c, const float* __restrict__ d,
    ushort* __restrict__ oa, ushort* __restrict__ ob,
    ushort* __restrict__ oc, ushort* __restrict__ od)
{
  int i = blockIdx.x * 256 + threadIdx.x;  // 262144 total
  if (i < 196608) { int r = i >> 8, k = i & 255; oa[(r << 8) + swz(k, r & 7)] = f2bf(a[i]); }
  if (i <  65536) { int r = i >> 8, k = i & 255; ob[(r << 8) + swz(k, r & 7)] = f2bf(b[i]); }
  { int r = i >> 8,  k = i & 255;  oc[(r << 8)  + swz(k, r & 7)] = f2bf(c[i]); }
  { int r = i >> 10, k = i & 1023; od[(r << 10) + swz(k, r & 7)] = f2bf(d[i]); }
}

// -------- 0b. pos table [1024][256] --------
__global__ __launch_bounds__(256) void pos_kernel(float* __restrict__ pos)
{
  int s = blockIdx.x, c = threadIdx.x;
  int hh = s >> 5, w = s & 31;
  const float sc = 6.28318530717958647692f / (32.0f + 1e-6f);
  int cc = c; float e;
  if (cc < 128) { e = (float)(hh + 1) * sc; }
  else          { e = (float)(w  + 1) * sc; cc -= 128; }
  int j = cc >> 1;
  float arg = e * exp2f((float)j * -0.20762050593046014f);  // 10000^(-j/64)
  pos[s * 256 + c] = (cc & 1) ? cosf(arg) : sinf(arg);
}

// -------- 1. f[row][c] = x/y transposed + 0.1*pos (f32 + swizzled bf16) --------
__global__ __launch_bounds__(256) void build_f_kernel(
    const float* __restrict__ x, const float* __restrict__ y,
    const float* __restrict__ pos,
    float* __restrict__ f, ushort* __restrict__ fb)
{
  __shared__ float T[64][65];
  int bx = blockIdx.x;                    // 8b * 16st * 4ct = 512
  int b = bx >> 6, st = (bx >> 2) & 15, ct = bx & 3;
  const float* src = (b < 4) ? x : y;
  int bb = b & 3;
  int tid = threadIdx.x;
  {
    int sl = tid & 63, c4 = tid >> 6;
    int s = st * 64 + sl;
    #pragma unroll
    for (int k = 0; k < 16; ++k) {
      int cl = c4 * 16 + k;
      T[cl][sl] = src[((size_t)((bb << 8) + ct * 64 + cl) << 10) + s];
    }
  }
  __syncthreads();
  {
    int cl = tid & 63, s4 = tid >> 6;
    int c = ct * 64 + cl;
    #pragma unroll
    for (int k = 0; k < 16; ++k) {
      int sl = s4 * 16 + k;
      int s = st * 64 + sl;
      float v = T[cl][sl] + 0.1f * pos[s * 256 + c];
      size_t row = (size_t)b * 1024 + s;
      f[row * 256 + c] = v;
      fb[row * 256 + swz(c, s & 7)] = f2bf(v);
    }
  }
}

// -------- 2. MFMA GEMM, global_load_lds staging, pre-swizzled inputs --------
// OUT_MODE: 0 = f32 linear, 1 = bf16 linear, 2 = bf16 swizzled
template<int BM, int OUT_MODE, int RELU>
__global__ __launch_bounds__(256) void gemm_mfma_kernel(
    const ushort* __restrict__ A, const ushort* __restrict__ B,
    const float* __restrict__ bias, void* __restrict__ Cout,
    int M, int N, int K)
{
  constexpr int MI = BM / 32;       // m-frags per wave
  __shared__ ushort Asw[BM * 64];
  __shared__ ushort Bsw[128 * 64];
  const int tid = threadIdx.x, lane = tid & 63, w = tid >> 6;
  const int m0 = blockIdx.y * BM, n0 = blockIdx.x * 128;
  const int wm0 = (w & 1) * (BM / 2), wn0 = (w >> 1) * 64;
  const int l15 = lane & 15, g = lane >> 4;
  const int r8 = lane >> 3, s8 = lane & 7;
  f32x4 acc[MI][4];
  #pragma unroll
  for (int i = 0; i < MI; ++i)
    #pragma unroll
    for (int j = 0; j < 4; ++j) acc[i][j] = (f32x4){0.f, 0.f, 0.f, 0.f};

  for (int kt = 0; kt < K; kt += 64) {
    __syncthreads();
    #pragma unroll
    for (int i = 0; i < BM / 32; ++i) {
      int row0 = w * (BM / 4) + i * 8;
      gld_lds16(A + (size_t)(m0 + row0 + r8) * K + kt + s8 * 8, &Asw[row0 * 64]);
    }
    #pragma unroll
    for (int i = 0; i < 4; ++i) {
      int row0 = w * 32 + i * 8;
      gld_lds16(B + (size_t)(n0 + row0 + r8) * K + kt + s8 * 8, &Bsw[row0 * 64]);
    }
    __syncthreads();
    #pragma unroll
    for (int ks = 0; ks < 2; ++ks) {
      bf16x8 af[MI], bfr[4];
      #pragma unroll
      for (int i = 0; i < MI; ++i) {
        int ra = wm0 + i * 16 + l15;
        af[i] = *(const bf16x8*)&Asw[ra * 64 + (((ks * 4 + g) ^ (ra & 7)) * 8)];
      }
      #pragma unroll
      for (int i = 0; i < 4; ++i) {
        int rb = wn0 + i * 16 + l15;
        bfr[i] = *(const bf16x8*)&Bsw[rb * 64 + (((ks * 4 + g) ^ (rb & 7)) * 8)];
      }
      #pragma unroll
      for (int mi = 0; mi < MI; ++mi)
        #pragma unroll
        for (int ni = 0; ni < 4; ++ni)
          acc[mi][ni] = __builtin_amdgcn_mfma_f32_16x16x32_bf16(
              af[mi], bfr[ni], acc[mi][ni], 0, 0, 0);
    }
  }

  float bv[4];
  #pragma unroll
  for (int ni = 0; ni < 4; ++ni) bv[ni] = bias[n0 + wn0 + ni * 16 + l15];
  #pragma unroll
  for (int mi = 0; mi < MI; ++mi)
    #pragma unroll
    for (int ni = 0; ni < 4; ++ni)
      #pragma unroll
      for (int r = 0; r < 4; ++r) {
        float v = acc[mi][ni][r] + bv[ni];
        if (RELU) v = fmaxf(v, 0.0f);
        size_t m = m0 + wm0 + mi * 16 + g * 4 + r;
        int n = n0 + wn0 + ni * 16 + l15;
        if (OUT_MODE == 0)      ((float*) Cout)[m * N + n] = v;
        else if (OUT_MODE == 1) ((ushort*)Cout)[m * N + n] = f2bf(v);
        else                    ((ushort*)Cout)[m * N + swz(n, (int)(m & 7))] = f2bf(v);
      }
}

// -------- 3. V transpose: qkv V-part -> vt[bh][d=32][t=1024], swizzled t-blocks --------
__global__ __launch_bounds__(256) void vtrans_kernel(
    const ushort* __restrict__ qkv, ushort* __restrict__ vt)
{
  __shared__ ushort T[64 * 40];
  int kv = blockIdx.x * 64;               // 16
  int bh = blockIdx.y;                    // 64
  int b = bh >> 3, h = bh & 7;
  size_t base = (size_t)b * SEQ * 768 + 512 + h * 32;
  int tid = threadIdx.x;
  {
    int row = tid >> 2, q = tid & 3;
    uint4 v = *(const uint4*)&qkv[base + (size_t)(kv + row) * 768 + q * 8];
    *(uint4*)&T[row * 40 + q * 8] = v;
  }
  __syncthreads();
  {
    int d = tid & 31, s8 = tid >> 5;
    union { ushort u[8]; uint4 v; } pk;
    #pragma unroll
    for (int j = 0; j < 8; ++j) pk.u[j] = T[(s8 * 8 + j) * 40 + d];
    *(uint4*)&vt[((size_t)bh * 32 + d) * 1024 + kv + (s8 ^ (d & 7)) * 8] = pk.v;
  }
}

// -------- 4. MFMA flash attention, dbuf K/V prefetch, defer-max --------
__global__ __launch_bounds__(256) void attn_mfma_kernel(
    const ushort* __restrict__ qkv, const ushort* __restrict__ vtg,
    ushort* __restrict__ attout)
{
  __shared__ ushort Qs[128 * 32];
  __shared__ ushort Ks[2][64 * 32];
  __shared__ ushort Vt[2][32 * 64];
  __shared__ ushort Ps[4][32 * 64];
  const int tid = threadIdx.x, lane = tid & 63, w = tid >> 6;
  const int l15 = lane & 15, g = lane >> 4;
  const int qt = blockIdx.x, h = blockIdx.y, b = blockIdx.z;
  const size_t base = (size_t)b * SEQ * 768;
  const int q0 = qt * 128, wq0 = w * 32;
  const int bh = b * 8 + h;
  const float sc = 0.25507964954389985f;   // (1/sqrt(32)) * log2(e)

  #pragma unroll
  for (int i = 0; i < 2; ++i) {
    int ch = 2 * w + i;
    gld_lds16(qkv + base + (size_t)(q0 + ch * 16 + (lane >> 2)) * 768 + h * 32 + (lane & 3) * 8,
              &Qs[ch * 16 * 32]);
  }
  gld_lds16(qkv + base + (size_t)(w * 16 + (lane >> 2)) * 768 + 256 + h * 32 + (lane & 3) * 8,
            &Ks[0][w * 16 * 32]);
  gld_lds16(vtg + ((size_t)bh * 32 + w * 8 + (lane >> 3)) * 1024 + (lane & 7) * 8,
            &Vt[0][w * 8 * 64]);
  __syncthreads();

  bf16x8 qf[2];
  #pragma unroll
  for (int qi = 0; qi < 2; ++qi)
    qf[qi] = *(const bf16x8*)&Qs[(wq0 + qi * 16 + l15) * 32 + g * 8];

  float m_[2] = {-1e30f, -1e30f}, l_[2] = {0.f, 0.f};
  f32x4 o[2][2];
  #pragma unroll
  for (int a = 0; a < 2; ++a)
    #pragma unroll
    for (int d = 0; d < 2; ++d) o[a][d] = (f32x4){0.f, 0.f, 0.f, 0.f};
  const f32x4 zero = (f32x4){0.f, 0.f, 0.f, 0.f};

  int cur = 0;
  for (int t = 0; t < 16; ++t) {
    if (t < 15) {                          // prefetch next K/V tile
      int nkv = t * 64 + 64;
      gld_lds16(qkv + base + (size_t)(nkv + w * 16 + (lane >> 2)) * 768 + 256 + h * 32 + (lane & 3) * 8,
                &Ks[cur ^ 1][w * 16 * 32]);
      gld_lds16(vtg + ((size_t)bh * 32 + w * 8 + (lane >> 3)) * 1024 + nkv + (lane & 7) * 8,
                &Vt[cur ^ 1][w * 8 * 64]);
    }
    // S^T = K . Q^T : lane owns q = qi*16+l15, t-rows g*4+r per ti
    bf16x8 kf[4];
    #pragma unroll
    for (int ti = 0; ti < 4; ++ti)
      kf[ti] = *(const bf16x8*)&Ks[cur][(ti * 16 + l15) * 32 + g * 8];
    f32x4 s[4][2];
    #pragma unroll
    for (int ti = 0; ti < 4; ++ti)
      #pragma unroll
      for (int qi = 0; qi < 2; ++qi)
        s[ti][qi] = __builtin_amdgcn_mfma_f32_16x16x32_bf16(kf[ti], qf[qi], zero, 0, 0, 0);

    #pragma unroll
    for (int qi = 0; qi < 2; ++qi) {
      float mx = s[0][qi][0];
      #pragma unroll
      for (int ti = 0; ti < 4; ++ti)
        #pragma unroll
        for (int r = 0; r < 4; ++r) if (ti + r) mx = fmaxf(mx, s[ti][qi][r]);
      mx = fmaxf(mx, __shfl_xor(mx, 16));
      mx = fmaxf(mx, __shfl_xor(mx, 32));
      if (!__all(mx <= m_[qi] + 31.36f)) {   // defer-max: 8/sc in raw-score units
        float mnew = fmaxf(m_[qi], mx);
        float corr = exp2f((m_[qi] - mnew) * sc);
        l_[qi] *= corr;
        #pragma unroll
        for (int r = 0; r < 4; ++r) {
          float cr = __shfl(corr, g * 4 + r);
          o[qi][0][r] *= cr; o[qi][1][r] *= cr;
        }
        m_[qi] = mnew;
      }
      float rs = 0.f;
      int q = qi * 16 + l15;
      #pragma unroll
      for (int ti = 0; ti < 4; ++ti) {
        ushort pb[4];
        #pragma unroll
        for (int r = 0; r < 4; ++r) {
          float p = exp2f((s[ti][qi][r] - m_[qi]) * sc);
          rs += p;
          pb[r] = f2bf(p);
        }
        int sw = (ti * 2 + (g >> 1)) ^ (q & 7);
        uint2 val;
        val.x = (unsigned)pb[0] | ((unsigned)pb[1] << 16);
        val.y = (unsigned)pb[2] | ((unsigned)pb[3] << 16);
        *(uint2*)&Ps[w][q * 64 + sw * 8 + (g & 1) * 4] = val;
      }
      rs += __shfl_xor(rs, 16);
      rs += __shfl_xor(rs, 32);
      l_[qi] += rs;
    }

    // O += P . V
    bf16x8 pa[2][2], vb[2][2];
    #pragma unroll
    for (int mi = 0; mi < 2; ++mi)
      #pragma unroll
      for (int ks = 0; ks < 2; ++ks) {
        int q = mi * 16 + l15;
        pa[mi][ks] = *(const bf16x8*)&Ps[w][q * 64 + (((ks * 4 + g) ^ (q & 7)) * 8)];
      }
    #pragma unroll
    for (int ks = 0; ks < 2; ++ks)
      #pragma unroll
      for (int di = 0; di < 2; ++di) {
        int d = di * 16 + l15;
        vb[ks][di] = *(const bf16x8*)&Vt[cur][d * 64 + (((ks * 4 + g) ^ (d & 7)) * 8)];
      }
    #pragma unroll
    for (int mi = 0; mi < 2; ++mi)
      #pragma unroll
      for (int di = 0; di < 2; ++di)
        #pragma unroll
        for (int ks = 0; ks < 2; ++ks)
          o[mi][di] = __builtin_amdgcn_mfma_f32_16x16x32_bf16(
              pa[mi][ks], vb[ks][di], o[mi][di], 0, 0, 0);
    __syncthreads();
    cur ^= 1;
  }

  // normalize + store bf16 swizzled [8192][256]
  #pragma unroll
  for (int qi = 0; qi < 2; ++qi)
    #pragma unroll
    for (int r = 0; r < 4; ++r) {
      float lr = __shfl(l_[qi], g * 4 + r);
      float inv = 1.0f / lr;
      size_t row = (size_t)b * SEQ + q0 + wq0 + qi * 16 + g * 4 + r;
      int rw7 = (g * 4 + r) & 7;
      #pragma unroll
      for (int di = 0; di < 2; ++di) {
        int col = h * 32 + di * 16 + l15;
        attout[row * 256 + swz(col, rw7)] = f2bf(o[qi][di][r] * inv);
      }
    }
}

// -------- 5. residual + LN (f32 + swizzled bf16) --------
__global__ __launch_bounds__(256) void add_ln_dual_kernel(
    const float* __restrict__ A, const float* __restrict__ R,
    const float* __restrict__ g, const float* __restrict__ bta,
    float* __restrict__ out, ushort* __restrict__ outb)
{
  __shared__ float sm[8];
  int row = blockIdx.x, c = threadIdx.x;
  size_t idx = (size_t)row * D_MODEL + c;
  float v = A[idx] + R[idx];
  float s = v;
  #pragma unroll
  for (int off = 32; off >= 1; off >>= 1) s += __shfl_down(s, off);
  if ((c & 63) == 0) sm[c >> 6] = s;
  __syncthreads();
  if (c == 0) sm[0] = (sm[0] + sm[1] + sm[2] + sm[3]) * (1.0f / 256.0f);
  __syncthreads();
  float mu = sm[0];
  float d = v - mu;
  float s2 = d * d;
  #pragma unroll
  for (int off = 32; off >= 1; off >>= 1) s2 += __shfl_down(s2, off);
  if ((c & 63) == 0) sm[4 + (c >> 6)] = s2;
  __syncthreads();
  if (c == 0) sm[1] = rsqrtf((sm[4] + sm[5] + sm[6] + sm[7]) * (1.0f / 256.0f) + 1e-5f);
  __syncthreads();
  float res = d * sm[1] * g[c] + bta[c];
  out[idx] = res;
  outb[(size_t)row * D_MODEL + swz(c, row & 7)] = f2bf(res);
}

// -------- 6. residual + LN + transpose-out (f32) --------
__global__ __launch_bounds__(256) void add_ln_out_kernel(
    const float* __restrict__ A, const float* __restrict__ R,
    const float* __restrict__ g, const float* __restrict__ bta,
    float* __restrict__ out)
{
  __shared__ float sm[8];
  int row = blockIdx.x, c = threadIdx.x;
  size_t idx = (size_t)row * D_MODEL + c;
  float v = A[idx] + R[idx];
  float s = v;
  #pragma unroll
  for (int off = 32; off >= 1; off >>= 1) s += __shfl_down(s, off);
  if ((c & 63) == 0) sm[c >> 6] = s;
  __syncthreads();
  if (c == 0) sm[0] = (sm[0] + sm[1] + sm[2] + sm[3]) * (1.0f / 256.0f);
  __syncthreads();
  float mu = sm[0];
  float d = v - mu;
  float s2 = d * d;
  #pragma unroll
  for (int off = 32; off >= 1; off >>= 1) s2 += __shfl_down(s2, off);
  if ((c & 63) == 0) sm[4 + (c >> 6)] = s2;
  __syncthreads();
  if (c == 0) sm[1] = rsqrtf((sm[4] + sm[5] + sm[6] + sm[7]) * (1.0f / 256.0f) + 1e-5f);
  __syncthreads();
  float res = d * sm[1] * g[c] + bta[c];
  int b = row >> 10, sq = row & 1023;
  size_t dst;
  if (b < 4) dst = ((size_t)((b << 8) + c) << 10) + sq;
  else       dst = (size_t)1048576 + ((size_t)(((b - 4) << 8) + c) << 10) + sq;
  out[dst] = res;
}

extern "C" void kernel_launch(void* const* d_in, const int* in_sizes, int n_in,
                              void* d_out, int out_size, void* d_ws, size_t ws_size,
                              hipStream_t stream)
{
  const float* x    = (const float*)d_in[0];
  const float* y    = (const float*)d_in[1];
  const float* Wqkv = (const float*)d_in[3];
  const float* bqkv = (const float*)d_in[4];
  const float* Wo   = (const float*)d_in[5];
  const float* bo   = (const float*)d_in[6];
  const float* W1   = (const float*)d_in[7];
  const float* b1   = (const float*)d_in[8];
  const float* W2   = (const float*)d_in[9];
  const float* b2   = (const float*)d_in[10];
  const float* g1   = (const float*)d_in[11];
  const float* be1  = (const float*)d_in[12];
  const float* g2   = (const float*)d_in[13];
  const float* be2  = (const float*)d_in[14];

  float* ws = (float*)d_ws;
  float*  f      = ws;                            // [0, 2M) f32
  ushort* f_bf   = (ushort*)(ws + 2097152);       // [2M, 3M) swizzled
  ushort* qkv_bf = (ushort*)(ws + 3145728);       // [3M, 6M) linear
  ushort* att_bf = (ushort*)(ws + 6291456);       // [6M, 7M) swizzled
  float*  tmp    = ws + 7340032;                  // [7M, 9M)
  float*  pos    = ws + 7340032;                  // overlaps tmp (dead before gemm2)
  ushort* vt_g   = (ushort*)(ws + 7602176);       // 2M ushorts, in tmp region
  float*  f1     = ws + 9437184;                  // [9M, 11M)
  ushort* f1_bf  = (ushort*)(ws + 11534336);      // [11M, 12M) swizzled
  ushort* h_bf   = (ushort*)(ws + 2097152);       // reuse [2M, 6M) swizzled
  float*  tmp2   = ws + 6291456;                  // reuse [6M, 8M)
  ushort* wq_bf  = (ushort*)(ws + 12582912);
  ushort* wo_bf  = wq_bf + 196608;
  ushort* w1_bf  = wo_bf + 65536;
  ushort* w2_bf  = w1_bf + 262144;

  conv_w_kernel<<<1024, 256, 0, stream>>>(Wqkv, Wo, W1, W2, wq_bf, wo_bf, w1_bf, w2_bf);
  pos_kernel<<<1024, 256, 0, stream>>>(pos);
  build_f_kernel<<<512, 256, 0, stream>>>(x, y, pos, f, f_bf);
  gemm_mfma_kernel<128, 1, 0><<<dim3(6, 64), 256, 0, stream>>>(f_bf, wq_bf, bqkv, qkv_bf, NROWS, 768, 256);
  vtrans_kernel<<<dim3(16, 64), 256, 0, stream>>>(qkv_bf, vt_g);
  attn_mfma_kernel<<<dim3(8, 8, 8), 256, 0, stream>>>(qkv_bf, vt_g, att_bf);
  gemm_mfma_kernel<64, 0, 0><<<dim3(2, 128), 256, 0, stream>>>(att_bf, wo_bf, bo, tmp, NROWS, 256, 256);
  add_ln_dual_kernel<<<8192, 256, 0, stream>>>(tmp, f, g1, be1, f1, f1_bf);
  gemm_mfma_kernel<128, 2, 1><<<dim3(8, 64), 256, 0, stream>>>(f1_bf, w1_bf, b1, h_bf, NROWS, 1024, 256);
  gemm_mfma_kernel<64, 0, 0><<<dim3(2, 128), 256, 0, stream>>>(h_bf, w2_bf, b2, tmp2, NROWS, 256, 1024);
  add_ln_out_kernel<<<8192, 256, 0, stream>>>(tmp2, f1, g2, be2, (float*)d_out);
}

// Round 5
// 120.386 us; speedup vs baseline: 5.0492x; 1.1394x over previous
//
#include <hip/hip_runtime.h>

typedef __attribute__((ext_vector_type(8))) short bf16x8;
typedef __attribute__((ext_vector_type(4))) float f32x4;

#define D_MODEL 256
#define SEQ     1024
#define NROWS   8192

__device__ __forceinline__ ushort f2bf(float f) {
  unsigned u = __float_as_uint(f);
  unsigned r = (u + 0x7FFFu + ((u >> 16) & 1u)) >> 16;
  return (ushort)r;
}
__device__ __forceinline__ float bf2f(ushort b) {
  return __uint_as_float(((unsigned)b) << 16);
}

// async global->LDS, 16B per lane; dst = wave-uniform base + lane*16
__device__ __forceinline__ void gld_lds16(const void* g, void* l) {
  __builtin_amdgcn_global_load_lds(
      (const __attribute__((address_space(1))) void*)g,
      (__attribute__((address_space(3))) void*)l, 16, 0, 0);
}

// XOR-swizzle of 8-element blocks within 64-col groups
__device__ __forceinline__ int swz(int col, int row7) {
  return (col & ~63) | ((((col >> 3) & 7) ^ row7) << 3) | (col & 7);
}

// -------- 0. weights fp32 -> bf16, pre-swizzled --------
__global__ __launch_bounds__(256) void conv_w_kernel(
    const float* __restrict__ a, const float* __restrict__ b,
    const float* __restrict__ c, const float* __restrict__ d,
    ushort* __restrict__ oa, ushort* __restrict__ ob,
    ushort* __restrict__ oc, ushort* __restrict__ od)
{
  int i = blockIdx.x * 256 + threadIdx.x;  // 262144 total
  if (i < 196608) { int r = i >> 8, k = i & 255; oa[(r << 8) + swz(k, r & 7)] = f2bf(a[i]); }
  if (i <  65536) { int r = i >> 8, k = i & 255; ob[(r << 8) + swz(k, r & 7)] = f2bf(b[i]); }
  { int r = i >> 8,  k = i & 255;  oc[(r << 8)  + swz(k, r & 7)] = f2bf(c[i]); }
  { int r = i >> 10, k = i & 1023; od[(r << 10) + swz(k, r & 7)] = f2bf(d[i]); }
}

// -------- 0b. pos table [1024][256] --------
__global__ __launch_bounds__(256) void pos_kernel(float* __restrict__ pos)
{
  int s = blockIdx.x, c = threadIdx.x;
  int hh = s >> 5, w = s & 31;
  const float sc = 6.28318530717958647692f / (32.0f + 1e-6f);
  int cc = c; float e;
  if (cc < 128) { e = (float)(hh + 1) * sc; }
  else          { e = (float)(w  + 1) * sc; cc -= 128; }
  int j = cc >> 1;
  float arg = e * exp2f((float)j * -0.20762050593046014f);  // 10000^(-j/64)
  pos[s * 256 + c] = (cc & 1) ? cosf(arg) : sinf(arg);
}

// -------- 1. f[row][c] = x/y transposed + 0.1*pos (f32 + swizzled bf16) --------
__global__ __launch_bounds__(256) void build_f_kernel(
    const float* __restrict__ x, const float* __restrict__ y,
    const float* __restrict__ pos,
    float* __restrict__ f, ushort* __restrict__ fb)
{
  __shared__ float T[64][65];
  int bx = blockIdx.x;                    // 8b * 16st * 4ct = 512
  int b = bx >> 6, st = (bx >> 2) & 15, ct = bx & 3;
  const float* src = (b < 4) ? x : y;
  int bb = b & 3;
  int tid = threadIdx.x;
  {
    int sl = tid & 63, c4 = tid >> 6;
    int s = st * 64 + sl;
    #pragma unroll
    for (int k = 0; k < 16; ++k) {
      int cl = c4 * 16 + k;
      T[cl][sl] = src[((size_t)((bb << 8) + ct * 64 + cl) << 10) + s];
    }
  }
  __syncthreads();
  {
    int cl = tid & 63, s4 = tid >> 6;
    int c = ct * 64 + cl;
    #pragma unroll
    for (int k = 0; k < 16; ++k) {
      int sl = s4 * 16 + k;
      int s = st * 64 + sl;
      float v = T[cl][sl] + 0.1f * pos[s * 256 + c];
      size_t row = (size_t)b * 1024 + s;
      f[row * 256 + c] = v;
      fb[row * 256 + swz(c, s & 7)] = f2bf(v);
    }
  }
}

// -------- 2. MFMA GEMM (BN=128), global_load_lds staging, pre-swizzled inputs --------
// OUT_MODE: 1 = bf16 linear, 2 = bf16 swizzled
template<int BM, int OUT_MODE, int RELU>
__global__ __launch_bounds__(256) void gemm_mfma_kernel(
    const ushort* __restrict__ A, const ushort* __restrict__ B,
    const float* __restrict__ bias, void* __restrict__ Cout,
    int M, int N, int K)
{
  constexpr int MI = BM / 32;
  __shared__ ushort Asw[BM * 64];
  __shared__ ushort Bsw[128 * 64];
  const int tid = threadIdx.x, lane = tid & 63, w = tid >> 6;
  const int m0 = blockIdx.y * BM, n0 = blockIdx.x * 128;
  const int wm0 = (w & 1) * (BM / 2), wn0 = (w >> 1) * 64;
  const int l15 = lane & 15, g = lane >> 4;
  const int r8 = lane >> 3, s8 = lane & 7;
  f32x4 acc[MI][4];
  #pragma unroll
  for (int i = 0; i < MI; ++i)
    #pragma unroll
    for (int j = 0; j < 4; ++j) acc[i][j] = (f32x4){0.f, 0.f, 0.f, 0.f};

  for (int kt = 0; kt < K; kt += 64) {
    __syncthreads();
    #pragma unroll
    for (int i = 0; i < BM / 32; ++i) {
      int row0 = w * (BM / 4) + i * 8;
      gld_lds16(A + (size_t)(m0 + row0 + r8) * K + kt + s8 * 8, &Asw[row0 * 64]);
    }
    #pragma unroll
    for (int i = 0; i < 4; ++i) {
      int row0 = w * 32 + i * 8;
      gld_lds16(B + (size_t)(n0 + row0 + r8) * K + kt + s8 * 8, &Bsw[row0 * 64]);
    }
    __syncthreads();
    #pragma unroll
    for (int ks = 0; ks < 2; ++ks) {
      bf16x8 af[MI], bfr[4];
      #pragma unroll
      for (int i = 0; i < MI; ++i) {
        int ra = wm0 + i * 16 + l15;
        af[i] = *(const bf16x8*)&Asw[ra * 64 + (((ks * 4 + g) ^ (ra & 7)) * 8)];
      }
      #pragma unroll
      for (int i = 0; i < 4; ++i) {
        int rb = wn0 + i * 16 + l15;
        bfr[i] = *(const bf16x8*)&Bsw[rb * 64 + (((ks * 4 + g) ^ (rb & 7)) * 8)];
      }
      __builtin_amdgcn_s_setprio(1);
      #pragma unroll
      for (int mi = 0; mi < MI; ++mi)
        #pragma unroll
        for (int ni = 0; ni < 4; ++ni)
          acc[mi][ni] = __builtin_amdgcn_mfma_f32_16x16x32_bf16(
              af[mi], bfr[ni], acc[mi][ni], 0, 0, 0);
      __builtin_amdgcn_s_setprio(0);
    }
  }

  float bv[4];
  #pragma unroll
  for (int ni = 0; ni < 4; ++ni) bv[ni] = bias[n0 + wn0 + ni * 16 + l15];
  #pragma unroll
  for (int mi = 0; mi < MI; ++mi)
    #pragma unroll
    for (int ni = 0; ni < 4; ++ni)
      #pragma unroll
      for (int r = 0; r < 4; ++r) {
        float v = acc[mi][ni][r] + bv[ni];
        if (RELU) v = fmaxf(v, 0.0f);
        size_t m = m0 + wm0 + mi * 16 + g * 4 + r;
        int n = n0 + wn0 + ni * 16 + l15;
        if (OUT_MODE == 1) ((ushort*)Cout)[m * N + n] = f2bf(v);
        else               ((ushort*)Cout)[m * N + swz(n, (int)(m & 7))] = f2bf(v);
      }
}

// -------- 2b. MFMA GEMM (BM=32, BN=256=N) with fused residual+LayerNorm epilogue --------
// TRANS_OUT=0: out=f32 [8192][256] + outb=bf16 swizzled.  TRANS_OUT=1: transposed f32 d_out.
template<int TRANS_OUT>
__global__ __launch_bounds__(256) void gemm_ln_kernel(
    const ushort* __restrict__ A, const ushort* __restrict__ B,
    const float* __restrict__ bias, const float* __restrict__ R,
    const float* __restrict__ gamma, const float* __restrict__ beta,
    float* __restrict__ out, ushort* __restrict__ outb, int K)
{
  __shared__ ushort Asw[32 * 64];
  __shared__ ushort Bsw[256 * 64];
  __shared__ float red[4][32][2];
  const int tid = threadIdx.x, lane = tid & 63, w = tid >> 6;
  const int l15 = lane & 15, g4 = lane >> 4;
  const int r8 = lane >> 3, s8 = lane & 7;
  const int m0 = blockIdx.x * 32;
  const int wn0 = w * 64;
  f32x4 acc[2][4];
  #pragma unroll
  for (int i = 0; i < 2; ++i)
    #pragma unroll
    for (int j = 0; j < 4; ++j) acc[i][j] = (f32x4){0.f, 0.f, 0.f, 0.f};

  for (int kt = 0; kt < K; kt += 64) {
    __syncthreads();
    gld_lds16(A + (size_t)(m0 + w * 8 + r8) * K + kt + s8 * 8, &Asw[(w * 8) * 64]);
    #pragma unroll
    for (int i = 0; i < 8; ++i) {
      int row0 = w * 64 + i * 8;
      gld_lds16(B + (size_t)(row0 + r8) * K + kt + s8 * 8, &Bsw[row0 * 64]);
    }
    __syncthreads();
    #pragma unroll
    for (int ks = 0; ks < 2; ++ks) {
      bf16x8 af[2], bfr[4];
      #pragma unroll
      for (int mi = 0; mi < 2; ++mi) {
        int ra = mi * 16 + l15;
        af[mi] = *(const bf16x8*)&Asw[ra * 64 + (((ks * 4 + g4) ^ (ra & 7)) * 8)];
      }
      #pragma unroll
      for (int ni = 0; ni < 4; ++ni) {
        int rb = wn0 + ni * 16 + l15;
        bfr[ni] = *(const bf16x8*)&Bsw[rb * 64 + (((ks * 4 + g4) ^ (rb & 7)) * 8)];
      }
      __builtin_amdgcn_s_setprio(1);
      #pragma unroll
      for (int mi = 0; mi < 2; ++mi)
        #pragma unroll
        for (int ni = 0; ni < 4; ++ni)
          acc[mi][ni] = __builtin_amdgcn_mfma_f32_16x16x32_bf16(
              af[mi], bfr[ni], acc[mi][ni], 0, 0, 0);
      __builtin_amdgcn_s_setprio(0);
    }
  }

  // epilogue: v = acc + bias + residual; LN over the 256 cols of each row
  float bv[4], gv[4], bev[4];
  #pragma unroll
  for (int ni = 0; ni < 4; ++ni) {
    int n = wn0 + ni * 16 + l15;
    bv[ni] = bias[n]; gv[ni] = gamma[n]; bev[ni] = beta[n];
  }
  float s1[2][4], s2[2][4];
  #pragma unroll
  for (int mi = 0; mi < 2; ++mi)
    #pragma unroll
    for (int r = 0; r < 4; ++r) { s1[mi][r] = 0.f; s2[mi][r] = 0.f; }
  #pragma unroll
  for (int mi = 0; mi < 2; ++mi)
    #pragma unroll
    for (int ni = 0; ni < 4; ++ni)
      #pragma unroll
      for (int r = 0; r < 4; ++r) {
        int row = m0 + mi * 16 + g4 * 4 + r;
        float v = acc[mi][ni][r] + bv[ni] + R[(size_t)row * 256 + wn0 + ni * 16 + l15];
        acc[mi][ni][r] = v;
        s1[mi][r] += v;
        s2[mi][r] += v * v;
      }
  #pragma unroll
  for (int mi = 0; mi < 2; ++mi)
    #pragma unroll
    for (int r = 0; r < 4; ++r) {
      #pragma unroll
      for (int d = 1; d < 16; d <<= 1) {
        s1[mi][r] += __shfl_xor(s1[mi][r], d);
        s2[mi][r] += __shfl_xor(s2[mi][r], d);
      }
    }
  if (l15 == 0) {
    #pragma unroll
    for (int mi = 0; mi < 2; ++mi)
      #pragma unroll
      for (int r = 0; r < 4; ++r) {
        int rl = mi * 16 + g4 * 4 + r;
        red[w][rl][0] = s1[mi][r];
        red[w][rl][1] = s2[mi][r];
      }
  }
  __syncthreads();
  #pragma unroll
  for (int mi = 0; mi < 2; ++mi)
    #pragma unroll
    for (int r = 0; r < 4; ++r) {
      int rl = mi * 16 + g4 * 4 + r;
      float t1 = red[0][rl][0] + red[1][rl][0] + red[2][rl][0] + red[3][rl][0];
      float t2 = red[0][rl][1] + red[1][rl][1] + red[2][rl][1] + red[3][rl][1];
      float mu = t1 * (1.0f / 256.0f);
      float var = t2 * (1.0f / 256.0f) - mu * mu;
      float rstd = rsqrtf(var + 1e-5f);
      int row = m0 + rl;
      #pragma unroll
      for (int ni = 0; ni < 4; ++ni) {
        int col = wn0 + ni * 16 + l15;
        float res = (acc[mi][ni][r] - mu) * rstd * gv[ni] + bev[ni];
        if (!TRANS_OUT) {
          out [(size_t)row * 256 + col] = res;
          outb[(size_t)row * 256 + swz(col, row & 7)] = f2bf(res);
        } else {
          int b = row >> 10, sq = row & 1023;
          size_t dst;
          if (b < 4) dst = ((size_t)((b << 8) + col) << 10) + sq;
          else       dst = (size_t)1048576 + ((size_t)(((b - 4) << 8) + col) << 10) + sq;
          out[dst] = res;
        }
      }
    }
}

// -------- 3. V transpose: qkv V-part -> vt[bh][d=32][t=1024], swizzled t-blocks --------
__global__ __launch_bounds__(256) void vtrans_kernel(
    const ushort* __restrict__ qkv, ushort* __restrict__ vt)
{
  __shared__ ushort T[64 * 40];
  int kv = blockIdx.x * 64;               // 16
  int bh = blockIdx.y;                    // 64
  int b = bh >> 3, h = bh & 7;
  size_t base = (size_t)b * SEQ * 768 + 512 + h * 32;
  int tid = threadIdx.x;
  {
    int row = tid >> 2, q = tid & 3;
    uint4 v = *(const uint4*)&qkv[base + (size_t)(kv + row) * 768 + q * 8];
    *(uint4*)&T[row * 40 + q * 8] = v;
  }
  __syncthreads();
  {
    int d = tid & 31, s8 = tid >> 5;
    union { ushort u[8]; uint4 v; } pk;
    #pragma unroll
    for (int j = 0; j < 8; ++j) pk.u[j] = T[(s8 * 8 + j) * 40 + d];
    *(uint4*)&vt[((size_t)bh * 32 + d) * 1024 + kv + (s8 ^ (d & 7)) * 8] = pk.v;
  }
}

// -------- 4. MFMA flash attention, KV-split x2, dbuf prefetch, defer-max --------
// writes unnormalized O (bf16) + per-(row,head) {m,l} (f32)
__global__ __launch_bounds__(256) void attn_mfma_kernel(
    const ushort* __restrict__ qkv, const ushort* __restrict__ vtg,
    ushort* __restrict__ po, float* __restrict__ pml)
{
  __shared__ ushort Qs[128 * 32];
  __shared__ ushort Ks[2][64 * 32];
  __shared__ ushort Vt[2][32 * 64];
  __shared__ ushort Ps[4][32 * 64];
  const int tid = threadIdx.x, lane = tid & 63, w = tid >> 6;
  const int l15 = lane & 15, g = lane >> 4;
  const int kvh = blockIdx.x & 1, qt = blockIdx.x >> 1;
  const int h = blockIdx.y, b = blockIdx.z;
  const size_t base = (size_t)b * SEQ * 768;
  const int q0 = qt * 128, wq0 = w * 32;
  const int bh = b * 8 + h;
  const int kvbase = kvh * 512;
  const float sc = 0.25507964954389985f;   // (1/sqrt(32)) * log2(e)

  #pragma unroll
  for (int i = 0; i < 2; ++i) {
    int ch = 2 * w + i;
    gld_lds16(qkv + base + (size_t)(q0 + ch * 16 + (lane >> 2)) * 768 + h * 32 + (lane & 3) * 8,
              &Qs[ch * 16 * 32]);
  }
  gld_lds16(qkv + base + (size_t)(kvbase + w * 16 + (lane >> 2)) * 768 + 256 + h * 32 + (lane & 3) * 8,
            &Ks[0][w * 16 * 32]);
  gld_lds16(vtg + ((size_t)bh * 32 + w * 8 + (lane >> 3)) * 1024 + kvbase + (lane & 7) * 8,
            &Vt[0][w * 8 * 64]);
  __syncthreads();

  bf16x8 qf[2];
  #pragma unroll
  for (int qi = 0; qi < 2; ++qi)
    qf[qi] = *(const bf16x8*)&Qs[(wq0 + qi * 16 + l15) * 32 + g * 8];

  float m_[2] = {-1e30f, -1e30f}, l_[2] = {0.f, 0.f};
  f32x4 o[2][2];
  #pragma unroll
  for (int a = 0; a < 2; ++a)
    #pragma unroll
    for (int d = 0; d < 2; ++d) o[a][d] = (f32x4){0.f, 0.f, 0.f, 0.f};
  const f32x4 zero = (f32x4){0.f, 0.f, 0.f, 0.f};

  int cur = 0;
  for (int t = 0; t < 8; ++t) {
    if (t < 7) {                           // prefetch next K/V tile
      int nkv = kvbase + t * 64 + 64;
      gld_lds16(qkv + base + (size_t)(nkv + w * 16 + (lane >> 2)) * 768 + 256 + h * 32 + (lane & 3) * 8,
                &Ks[cur ^ 1][w * 16 * 32]);
      gld_lds16(vtg + ((size_t)bh * 32 + w * 8 + (lane >> 3)) * 1024 + nkv + (lane & 7) * 8,
                &Vt[cur ^ 1][w * 8 * 64]);
    }
    bf16x8 kf[4];
    #pragma unroll
    for (int ti = 0; ti < 4; ++ti)
      kf[ti] = *(const bf16x8*)&Ks[cur][(ti * 16 + l15) * 32 + g * 8];
    f32x4 s[4][2];
    __builtin_amdgcn_s_setprio(1);
    #pragma unroll
    for (int ti = 0; ti < 4; ++ti)
      #pragma unroll
      for (int qi = 0; qi < 2; ++qi)
        s[ti][qi] = __builtin_amdgcn_mfma_f32_16x16x32_bf16(kf[ti], qf[qi], zero, 0, 0, 0);
    __builtin_amdgcn_s_setprio(0);

    #pragma unroll
    for (int qi = 0; qi < 2; ++qi) {
      float mx = s[0][qi][0];
      #pragma unroll
      for (int ti = 0; ti < 4; ++ti)
        #pragma unroll
        for (int r = 0; r < 4; ++r) if (ti + r) mx = fmaxf(mx, s[ti][qi][r]);
      mx = fmaxf(mx, __shfl_xor(mx, 16));
      mx = fmaxf(mx, __shfl_xor(mx, 32));
      if (!__all(mx <= m_[qi] + 31.36f)) {   // defer-max: 8/sc raw-score units
        float mnew = fmaxf(m_[qi], mx);
        float corr = exp2f((m_[qi] - mnew) * sc);
        l_[qi] *= corr;
        #pragma unroll
        for (int r = 0; r < 4; ++r) {
          float cr = __shfl(corr, g * 4 + r);
          o[qi][0][r] *= cr; o[qi][1][r] *= cr;
        }
        m_[qi] = mnew;
      }
      float rs = 0.f;
      int q = qi * 16 + l15;
      #pragma unroll
      for (int ti = 0; ti < 4; ++ti) {
        ushort pb[4];
        #pragma unroll
        for (int r = 0; r < 4; ++r) {
          float p = exp2f((s[ti][qi][r] - m_[qi]) * sc);
          rs += p;
          pb[r] = f2bf(p);
        }
        int sw = (ti * 2 + (g >> 1)) ^ (q & 7);
        uint2 val;
        val.x = (unsigned)pb[0] | ((unsigned)pb[1] << 16);
        val.y = (unsigned)pb[2] | ((unsigned)pb[3] << 16);
        *(uint2*)&Ps[w][q * 64 + sw * 8 + (g & 1) * 4] = val;
      }
      rs += __shfl_xor(rs, 16);
      rs += __shfl_xor(rs, 32);
      l_[qi] += rs;
    }

    bf16x8 pa[2][2], vb[2][2];
    #pragma unroll
    for (int mi = 0; mi < 2; ++mi)
      #pragma unroll
      for (int ks = 0; ks < 2; ++ks) {
        int q = mi * 16 + l15;
        pa[mi][ks] = *(const bf16x8*)&Ps[w][q * 64 + (((ks * 4 + g) ^ (q & 7)) * 8)];
      }
    #pragma unroll
    for (int ks = 0; ks < 2; ++ks)
      #pragma unroll
      for (int di = 0; di < 2; ++di) {
        int d = di * 16 + l15;
        vb[ks][di] = *(const bf16x8*)&Vt[cur][d * 64 + (((ks * 4 + g) ^ (d & 7)) * 8)];
      }
    __builtin_amdgcn_s_setprio(1);
    #pragma unroll
    for (int mi = 0; mi < 2; ++mi)
      #pragma unroll
      for (int di = 0; di < 2; ++di)
        #pragma unroll
        for (int ks = 0; ks < 2; ++ks)
          o[mi][di] = __builtin_amdgcn_mfma_f32_16x16x32_bf16(
              pa[mi][ks], vb[ks][di], o[mi][di], 0, 0, 0);
    __builtin_amdgcn_s_setprio(0);
    __syncthreads();
    cur ^= 1;
  }

  // store partials: unnormalized O (bf16) + m/l (f32, one copy per q-row)
  #pragma unroll
  for (int qi = 0; qi < 2; ++qi) {
    if (g == 0) {
      size_t qrow = (size_t)b * SEQ + q0 + wq0 + qi * 16 + l15;
      size_t idx = ((size_t)kvh * NROWS + qrow) * 16 + h * 2;
      pml[idx] = m_[qi];
      pml[idx + 1] = l_[qi];
    }
    #pragma unroll
    for (int r = 0; r < 4; ++r) {
      size_t row = (size_t)b * SEQ + q0 + wq0 + qi * 16 + g * 4 + r;
      #pragma unroll
      for (int di = 0; di < 2; ++di) {
        int col = h * 32 + di * 16 + l15;
        po[(size_t)kvh * 2097152 + row * 256 + col] = f2bf(o[qi][di][r]);
      }
    }
  }
}

// -------- 4b. combine the two KV halves --------
__global__ __launch_bounds__(256) void attn_combine_kernel(
    const ushort* __restrict__ po, const float* __restrict__ pml,
    ushort* __restrict__ att)
{
  const float sc = 0.25507964954389985f;
  int row = blockIdx.x, c = threadIdx.x, h = c >> 5;
  size_t i1 = (size_t)row * 16 + h * 2;
  size_t i2 = ((size_t)NROWS + row) * 16 + h * 2;
  float m1 = pml[i1], l1 = pml[i1 + 1];
  float m2 = pml[i2], l2 = pml[i2 + 1];
  float m = fmaxf(m1, m2);
  float w1 = exp2f((m1 - m) * sc), w2 = exp2f((m2 - m) * sc);
  float o1 = bf2f(po[(size_t)row * 256 + c]);
  float o2 = bf2f(po[(size_t)2097152 + row * 256 + c]);
  float v = (w1 * o1 + w2 * o2) / (w1 * l1 + w2 * l2);
  att[(size_t)row * 256 + swz(c, row & 7)] = f2bf(v);
}

extern "C" void kernel_launch(void* const* d_in, const int* in_sizes, int n_in,
                              void* d_out, int out_size, void* d_ws, size_t ws_size,
                              hipStream_t stream)
{
  const float* x    = (const float*)d_in[0];
  const float* y    = (const float*)d_in[1];
  const float* Wqkv = (const float*)d_in[3];
  const float* bqkv = (const float*)d_in[4];
  const float* Wo   = (const float*)d_in[5];
  const float* bo   = (const float*)d_in[6];
  const float* W1   = (const float*)d_in[7];
  const float* b1   = (const float*)d_in[8];
  const float* W2   = (const float*)d_in[9];
  const float* b2   = (const float*)d_in[10];
  const float* g1   = (const float*)d_in[11];
  const float* be1  = (const float*)d_in[12];
  const float* g2   = (const float*)d_in[13];
  const float* be2  = (const float*)d_in[14];

  float* ws = (float*)d_ws;
  float*  f      = ws;                            // [0, 2M) f32
  ushort* f_bf   = (ushort*)(ws + 2097152);       // [2M, 3M) swizzled
  ushort* qkv_bf = (ushort*)(ws + 3145728);       // [3M, 6M) linear
  ushort* att_bf = (ushort*)(ws + 6291456);       // [6M, 7M) swizzled
  ushort* po     = (ushort*)(ws + 7340032);       // [7M, 9M) 2 planes of 2M bf16
  float*  pos    = ws + 7340032;                  // overlaps po (dead before attn)
  float*  pml    = ws + 9437184;                  // [9M, 9.25M)
  ushort* vt_g   = (ushort*)(ws + 9699328);       // [9.25M, 10.25M)
  float*  f1     = ws + 10747904;                 // [10.25M, 12.25M)
  ushort* f1_bf  = (ushort*)(ws + 12845056);      // [12.25M, 13.25M) swizzled
  ushort* h_bf   = (ushort*)(ws + 2097152);       // reuse [2M, 6M) swizzled
  ushort* wq_bf  = (ushort*)(ws + 13893632);
  ushort* wo_bf  = wq_bf + 196608;
  ushort* w1_bf  = wo_bf + 65536;
  ushort* w2_bf  = w1_bf + 262144;

  conv_w_kernel<<<1024, 256, 0, stream>>>(Wqkv, Wo, W1, W2, wq_bf, wo_bf, w1_bf, w2_bf);
  pos_kernel<<<1024, 256, 0, stream>>>(pos);
  build_f_kernel<<<512, 256, 0, stream>>>(x, y, pos, f, f_bf);
  gemm_mfma_kernel<128, 1, 0><<<dim3(6, 64), 256, 0, stream>>>(f_bf, wq_bf, bqkv, qkv_bf, NROWS, 768, 256);
  vtrans_kernel<<<dim3(16, 64), 256, 0, stream>>>(qkv_bf, vt_g);
  attn_mfma_kernel<<<dim3(16, 8, 8), 256, 0, stream>>>(qkv_bf, vt_g, po, pml);
  attn_combine_kernel<<<8192, 256, 0, stream>>>(po, pml, att_bf);
  gemm_ln_kernel<0><<<256, 256, 0, stream>>>(att_bf, wo_bf, bo, f, g1, be1, f1, f1_bf, 256);
  gemm_mfma_kernel<128, 2, 1><<<dim3(8, 64), 256, 0, stream>>>(f1_bf, w1_bf, b1, h_bf, NROWS, 1024, 256);
  gemm_ln_kernel<1><<<256, 256, 0, stream>>>(h_bf, w2_bf, b2, f1, g2, be2, (float*)d_out, nullptr, 1024);
}

// Round 6
// 113.561 us; speedup vs baseline: 5.3527x; 1.0601x over previous
//
#include <hip/hip_runtime.h>

typedef __attribute__((ext_vector_type(8))) short bf16x8;
typedef __attribute__((ext_vector_type(4))) float f32x4;

#define D_MODEL 256
#define SEQ     1024
#define NROWS   8192

__device__ __forceinline__ ushort f2bf(float f) {
  unsigned u = __float_as_uint(f);
  unsigned r = (u + 0x7FFFu + ((u >> 16) & 1u)) >> 16;
  return (ushort)r;
}
__device__ __forceinline__ float bf2f(ushort b) {
  return __uint_as_float(((unsigned)b) << 16);
}

// async global->LDS, 16B per lane; dst = wave-uniform base + lane*16
__device__ __forceinline__ void gld_lds16(const void* g, void* l) {
  __builtin_amdgcn_global_load_lds(
      (const __attribute__((address_space(1))) void*)g,
      (__attribute__((address_space(3))) void*)l, 16, 0, 0);
}

// XOR-swizzle of 8-element blocks within 64-col groups
__device__ __forceinline__ int swz(int col, int row7) {
  return (col & ~63) | ((((col >> 3) & 7) ^ row7) << 3) | (col & 7);
}

// -------- 0. prep: weights fp32 -> bf16 pre-swizzled  +  pos table --------
__global__ __launch_bounds__(256) void prep_kernel(
    const float* __restrict__ a, const float* __restrict__ b,
    const float* __restrict__ c, const float* __restrict__ d,
    ushort* __restrict__ oa, ushort* __restrict__ ob,
    ushort* __restrict__ oc, ushort* __restrict__ od,
    float* __restrict__ pos)
{
  int i = blockIdx.x * 256 + threadIdx.x;  // 262144 total
  if (i < 196608) { int r = i >> 8, k = i & 255; oa[(r << 8) + swz(k, r & 7)] = f2bf(a[i]); }
  if (i <  65536) { int r = i >> 8, k = i & 255; ob[(r << 8) + swz(k, r & 7)] = f2bf(b[i]); }
  { int r = i >> 8,  k = i & 255;  oc[(r << 8)  + swz(k, r & 7)] = f2bf(c[i]); }
  { int r = i >> 10, k = i & 1023; od[(r << 10) + swz(k, r & 7)] = f2bf(d[i]); }
  // pos
  {
    int s = i >> 8, cc = i & 255;
    int hh = s >> 5, w = s & 31;
    const float sc = 6.28318530717958647692f / (32.0f + 1e-6f);
    float e;
    int c2 = cc;
    if (c2 < 128) { e = (float)(hh + 1) * sc; }
    else          { e = (float)(w  + 1) * sc; c2 -= 128; }
    int j = c2 >> 1;
    float arg = e * exp2f((float)j * -0.20762050593046014f);  // 10000^(-j/64)
    pos[i] = (c2 & 1) ? cosf(arg) : sinf(arg);
  }
}

// -------- 1. f_bf[row][swz(c)] = transpose(x/y) + 0.1*pos  (bf16 only) --------
__global__ __launch_bounds__(256) void build_f_kernel(
    const float* __restrict__ x, const float* __restrict__ y,
    const float* __restrict__ pos, ushort* __restrict__ fb)
{
  __shared__ float T[64][65];
  int bx = blockIdx.x;                    // 8b * 16st * 4ct = 512
  int b = bx >> 6, st = (bx >> 2) & 15, ct = bx & 3;
  const float* src = (b < 4) ? x : y;
  int bb = b & 3;
  int tid = threadIdx.x;
  {
    int sl = tid & 63, c4 = tid >> 6;
    int s = st * 64 + sl;
    #pragma unroll
    for (int k = 0; k < 16; ++k) {
      int cl = c4 * 16 + k;
      T[cl][sl] = src[((size_t)((bb << 8) + ct * 64 + cl) << 10) + s];
    }
  }
  __syncthreads();
  {
    int cl = tid & 63, s4 = tid >> 6;
    int c = ct * 64 + cl;
    #pragma unroll
    for (int k = 0; k < 16; ++k) {
      int sl = s4 * 16 + k;
      int s = st * 64 + sl;
      float v = T[cl][sl] + 0.1f * pos[s * 256 + c];
      size_t row = (size_t)b * 1024 + s;
      fb[row * 256 + swz(c, s & 7)] = f2bf(v);
    }
  }
}

// -------- 2. MFMA GEMM (BN=128), global_load_lds, pre-swizzled inputs --------
// OUT_MODE: 1 = bf16 linear, 2 = bf16 swizzled
template<int BM, int OUT_MODE, int RELU>
__global__ __launch_bounds__(256) void gemm_mfma_kernel(
    const ushort* __restrict__ A, const ushort* __restrict__ B,
    const float* __restrict__ bias, void* __restrict__ Cout,
    int M, int N, int K)
{
  constexpr int MI = BM / 32;
  __shared__ ushort Asw[BM * 64];
  __shared__ ushort Bsw[128 * 64];
  const int tid = threadIdx.x, lane = tid & 63, w = tid >> 6;
  const int m0 = blockIdx.y * BM, n0 = blockIdx.x * 128;
  const int wm0 = (w & 1) * (BM / 2), wn0 = (w >> 1) * 64;
  const int l15 = lane & 15, g = lane >> 4;
  const int r8 = lane >> 3, s8 = lane & 7;
  f32x4 acc[MI][4];
  #pragma unroll
  for (int i = 0; i < MI; ++i)
    #pragma unroll
    for (int j = 0; j < 4; ++j) acc[i][j] = (f32x4){0.f, 0.f, 0.f, 0.f};

  for (int kt = 0; kt < K; kt += 64) {
    __syncthreads();
    #pragma unroll
    for (int i = 0; i < BM / 32; ++i) {
      int row0 = w * (BM / 4) + i * 8;
      gld_lds16(A + (size_t)(m0 + row0 + r8) * K + kt + s8 * 8, &Asw[row0 * 64]);
    }
    #pragma unroll
    for (int i = 0; i < 4; ++i) {
      int row0 = w * 32 + i * 8;
      gld_lds16(B + (size_t)(n0 + row0 + r8) * K + kt + s8 * 8, &Bsw[row0 * 64]);
    }
    __syncthreads();
    #pragma unroll
    for (int ks = 0; ks < 2; ++ks) {
      bf16x8 af[MI], bfr[4];
      #pragma unroll
      for (int i = 0; i < MI; ++i) {
        int ra = wm0 + i * 16 + l15;
        af[i] = *(const bf16x8*)&Asw[ra * 64 + (((ks * 4 + g) ^ (ra & 7)) * 8)];
      }
      #pragma unroll
      for (int i = 0; i < 4; ++i) {
        int rb = wn0 + i * 16 + l15;
        bfr[i] = *(const bf16x8*)&Bsw[rb * 64 + (((ks * 4 + g) ^ (rb & 7)) * 8)];
      }
      __builtin_amdgcn_s_setprio(1);
      #pragma unroll
      for (int mi = 0; mi < MI; ++mi)
        #pragma unroll
        for (int ni = 0; ni < 4; ++ni)
          acc[mi][ni] = __builtin_amdgcn_mfma_f32_16x16x32_bf16(
              af[mi], bfr[ni], acc[mi][ni], 0, 0, 0);
      __builtin_amdgcn_s_setprio(0);
    }
  }

  float bv[4];
  #pragma unroll
  for (int ni = 0; ni < 4; ++ni) bv[ni] = bias[n0 + wn0 + ni * 16 + l15];
  #pragma unroll
  for (int mi = 0; mi < MI; ++mi)
    #pragma unroll
    for (int ni = 0; ni < 4; ++ni)
      #pragma unroll
      for (int r = 0; r < 4; ++r) {
        float v = acc[mi][ni][r] + bv[ni];
        if (RELU) v = fmaxf(v, 0.0f);
        size_t m = m0 + wm0 + mi * 16 + g * 4 + r;
        int n = n0 + wn0 + ni * 16 + l15;
        if (OUT_MODE == 1) ((ushort*)Cout)[m * N + n] = f2bf(v);
        else               ((ushort*)Cout)[m * N + swz(n, (int)(m & 7))] = f2bf(v);
      }
}

// -------- 2b. GEMM (BM=32, BN=256=N) + fused residual(bf16 swz) + LayerNorm --------
// TRANS_OUT=0: outb = bf16 swizzled.  TRANS_OUT=1: transposed f32 d_out.
template<int TRANS_OUT>
__global__ __launch_bounds__(256) void gemm_ln_kernel(
    const ushort* __restrict__ A, const ushort* __restrict__ B,
    const float* __restrict__ bias, const ushort* __restrict__ R,
    const float* __restrict__ gamma, const float* __restrict__ beta,
    float* __restrict__ out, ushort* __restrict__ outb, int K)
{
  __shared__ ushort Asw[32 * 64];
  __shared__ ushort Bsw[256 * 64];
  __shared__ float red[4][32][2];
  const int tid = threadIdx.x, lane = tid & 63, w = tid >> 6;
  const int l15 = lane & 15, g4 = lane >> 4;
  const int r8 = lane >> 3, s8 = lane & 7;
  const int m0 = blockIdx.x * 32;
  const int wn0 = w * 64;
  f32x4 acc[2][4];
  #pragma unroll
  for (int i = 0; i < 2; ++i)
    #pragma unroll
    for (int j = 0; j < 4; ++j) acc[i][j] = (f32x4){0.f, 0.f, 0.f, 0.f};

  for (int kt = 0; kt < K; kt += 64) {
    __syncthreads();
    gld_lds16(A + (size_t)(m0 + w * 8 + r8) * K + kt + s8 * 8, &Asw[(w * 8) * 64]);
    #pragma unroll
    for (int i = 0; i < 8; ++i) {
      int row0 = w * 64 + i * 8;
      gld_lds16(B + (size_t)(row0 + r8) * K + kt + s8 * 8, &Bsw[row0 * 64]);
    }
    __syncthreads();
    #pragma unroll
    for (int ks = 0; ks < 2; ++ks) {
      bf16x8 af[2], bfr[4];
      #pragma unroll
      for (int mi = 0; mi < 2; ++mi) {
        int ra = mi * 16 + l15;
        af[mi] = *(const bf16x8*)&Asw[ra * 64 + (((ks * 4 + g4) ^ (ra & 7)) * 8)];
      }
      #pragma unroll
      for (int ni = 0; ni < 4; ++ni) {
        int rb = wn0 + ni * 16 + l15;
        bfr[ni] = *(const bf16x8*)&Bsw[rb * 64 + (((ks * 4 + g4) ^ (rb & 7)) * 8)];
      }
      __builtin_amdgcn_s_setprio(1);
      #pragma unroll
      for (int mi = 0; mi < 2; ++mi)
        #pragma unroll
        for (int ni = 0; ni < 4; ++ni)
          acc[mi][ni] = __builtin_amdgcn_mfma_f32_16x16x32_bf16(
              af[mi], bfr[ni], acc[mi][ni], 0, 0, 0);
      __builtin_amdgcn_s_setprio(0);
    }
  }

  float bv[4], gv[4], bev[4];
  #pragma unroll
  for (int ni = 0; ni < 4; ++ni) {
    int n = wn0 + ni * 16 + l15;
    bv[ni] = bias[n]; gv[ni] = gamma[n]; bev[ni] = beta[n];
  }
  float s1[2][4], s2[2][4];
  #pragma unroll
  for (int mi = 0; mi < 2; ++mi)
    #pragma unroll
    for (int r = 0; r < 4; ++r) { s1[mi][r] = 0.f; s2[mi][r] = 0.f; }
  #pragma unroll
  for (int mi = 0; mi < 2; ++mi)
    #pragma unroll
    for (int ni = 0; ni < 4; ++ni)
      #pragma unroll
      for (int r = 0; r < 4; ++r) {
        int row = m0 + mi * 16 + g4 * 4 + r;
        int col = wn0 + ni * 16 + l15;
        float v = acc[mi][ni][r] + bv[ni] + bf2f(R[(size_t)row * 256 + swz(col, row & 7)]);
        acc[mi][ni][r] = v;
        s1[mi][r] += v;
        s2[mi][r] += v * v;
      }
  #pragma unroll
  for (int mi = 0; mi < 2; ++mi)
    #pragma unroll
    for (int r = 0; r < 4; ++r) {
      #pragma unroll
      for (int d = 1; d < 16; d <<= 1) {
        s1[mi][r] += __shfl_xor(s1[mi][r], d);
        s2[mi][r] += __shfl_xor(s2[mi][r], d);
      }
    }
  if (l15 == 0) {
    #pragma unroll
    for (int mi = 0; mi < 2; ++mi)
      #pragma unroll
      for (int r = 0; r < 4; ++r) {
        int rl = mi * 16 + g4 * 4 + r;
        red[w][rl][0] = s1[mi][r];
        red[w][rl][1] = s2[mi][r];
      }
  }
  __syncthreads();
  #pragma unroll
  for (int mi = 0; mi < 2; ++mi)
    #pragma unroll
    for (int r = 0; r < 4; ++r) {
      int rl = mi * 16 + g4 * 4 + r;
      float t1 = red[0][rl][0] + red[1][rl][0] + red[2][rl][0] + red[3][rl][0];
      float t2 = red[0][rl][1] + red[1][rl][1] + red[2][rl][1] + red[3][rl][1];
      float mu = t1 * (1.0f / 256.0f);
      float var = t2 * (1.0f / 256.0f) - mu * mu;
      float rstd = rsqrtf(var + 1e-5f);
      int row = m0 + rl;
      #pragma unroll
      for (int ni = 0; ni < 4; ++ni) {
        int col = wn0 + ni * 16 + l15;
        float res = (acc[mi][ni][r] - mu) * rstd * gv[ni] + bev[ni];
        if (!TRANS_OUT) {
          outb[(size_t)row * 256 + swz(col, row & 7)] = f2bf(res);
        } else {
          int b = row >> 10, sq = row & 1023;
          size_t dst;
          if (b < 4) dst = ((size_t)((b << 8) + col) << 10) + sq;
          else       dst = (size_t)1048576 + ((size_t)(((b - 4) << 8) + col) << 10) + sq;
          out[dst] = res;
        }
      }
    }
}

// -------- 3. V transpose: qkv V-part -> vt[bh][d=32][t=1024], swizzled t-blocks --------
__global__ __launch_bounds__(256) void vtrans_kernel(
    const ushort* __restrict__ qkv, ushort* __restrict__ vt)
{
  __shared__ ushort T[64 * 40];
  int kv = blockIdx.x * 64;               // 16
  int bh = blockIdx.y;                    // 64
  int b = bh >> 3, h = bh & 7;
  size_t base = (size_t)b * SEQ * 768 + 512 + h * 32;
  int tid = threadIdx.x;
  {
    int row = tid >> 2, q = tid & 3;
    uint4 v = *(const uint4*)&qkv[base + (size_t)(kv + row) * 768 + q * 8];
    *(uint4*)&T[row * 40 + q * 8] = v;
  }
  __syncthreads();
  {
    int d = tid & 31, s8 = tid >> 5;
    union { ushort u[8]; uint4 v; } pk;
    #pragma unroll
    for (int j = 0; j < 8; ++j) pk.u[j] = T[(s8 * 8 + j) * 40 + d];
    *(uint4*)&vt[((size_t)bh * 32 + d) * 1024 + kv + (s8 ^ (d & 7)) * 8] = pk.v;
  }
}

// -------- 4. MFMA flash attention, KV-split x4, Q in regs, swizzled K LDS --------
__global__ __launch_bounds__(256) void attn_mfma_kernel(
    const ushort* __restrict__ qkv, const ushort* __restrict__ vtg,
    ushort* __restrict__ po, float* __restrict__ pml)
{
  __shared__ ushort Ks[2][64 * 32];
  __shared__ ushort Vt[2][32 * 64];
  __shared__ ushort Ps[4][32 * 64];
  const int tid = threadIdx.x, lane = tid & 63, w = tid >> 6;
  const int l15 = lane & 15, g = lane >> 4;
  const int kvs = blockIdx.x & 3, qt = blockIdx.x >> 2;
  const int h = blockIdx.y, b = blockIdx.z;
  const size_t base = (size_t)b * SEQ * 768;
  const int q0 = qt * 128, wq0 = w * 32;
  const int bh = b * 8 + h;
  const int kvbase = kvs * 256;
  const float sc = 0.25507964954389985f;   // (1/sqrt(32)) * log2(e)

  // Q fragments direct from global (per-lane 16B gather, once)
  bf16x8 qf[2];
  #pragma unroll
  for (int qi = 0; qi < 2; ++qi)
    qf[qi] = *(const bf16x8*)&qkv[base + (size_t)(q0 + wq0 + qi * 16 + l15) * 768 + h * 32 + g * 8];

  // K stage: lane (r = lane>>2, qb = lane&3); source block pre-swizzled qb^(r&3)
  // so LDS[r][blk] = global[r][blk ^ (r&3)]
  {
    int r = lane >> 2, qb = lane & 3;
    gld_lds16(qkv + base + (size_t)(kvbase + w * 16 + r) * 768 + 256 + h * 32 + ((qb ^ (r & 3)) * 8),
              &Ks[0][w * 16 * 32]);
    gld_lds16(vtg + ((size_t)bh * 32 + w * 8 + (lane >> 3)) * 1024 + kvbase + (lane & 7) * 8,
              &Vt[0][w * 8 * 64]);
  }
  __syncthreads();

  float m_[2] = {-1e30f, -1e30f}, l_[2] = {0.f, 0.f};
  f32x4 o[2][2];
  #pragma unroll
  for (int a = 0; a < 2; ++a)
    #pragma unroll
    for (int d = 0; d < 2; ++d) o[a][d] = (f32x4){0.f, 0.f, 0.f, 0.f};
  const f32x4 zero = (f32x4){0.f, 0.f, 0.f, 0.f};

  int cur = 0;
  for (int t = 0; t < 4; ++t) {
    if (t < 3) {                           // prefetch next K/V tile
      int nkv = kvbase + t * 64 + 64;
      int r = lane >> 2, qb = lane & 3;
      gld_lds16(qkv + base + (size_t)(nkv + w * 16 + r) * 768 + 256 + h * 32 + ((qb ^ (r & 3)) * 8),
                &Ks[cur ^ 1][w * 16 * 32]);
      gld_lds16(vtg + ((size_t)bh * 32 + w * 8 + (lane >> 3)) * 1024 + nkv + (lane & 7) * 8,
                &Vt[cur ^ 1][w * 8 * 64]);
    }
    // S^T = K . Q^T : lane owns q = qi*16+l15, t = ti*16+g*4+r
    bf16x8 kf[4];
    #pragma unroll
    for (int ti = 0; ti < 4; ++ti) {
      int row = ti * 16 + l15;
      kf[ti] = *(const bf16x8*)&Ks[cur][row * 32 + ((g ^ (row & 3)) * 8)];
    }
    f32x4 s[4][2];
    __builtin_amdgcn_s_setprio(1);
    #pragma unroll
    for (int ti = 0; ti < 4; ++ti)
      #pragma unroll
      for (int qi = 0; qi < 2; ++qi)
        s[ti][qi] = __builtin_amdgcn_mfma_f32_16x16x32_bf16(kf[ti], qf[qi], zero, 0, 0, 0);
    __builtin_amdgcn_s_setprio(0);

    #pragma unroll
    for (int qi = 0; qi < 2; ++qi) {
      float mx = s[0][qi][0];
      #pragma unroll
      for (int ti = 0; ti < 4; ++ti)
        #pragma unroll
        for (int r = 0; r < 4; ++r) if (ti + r) mx = fmaxf(mx, s[ti][qi][r]);
      mx = fmaxf(mx, __shfl_xor(mx, 16));
      mx = fmaxf(mx, __shfl_xor(mx, 32));
      if (!__all(mx <= m_[qi] + 31.36f)) {   // defer-max: 8/sc raw-score units
        float mnew = fmaxf(m_[qi], mx);
        float corr = exp2f((m_[qi] - mnew) * sc);
        l_[qi] *= corr;
        #pragma unroll
        for (int r = 0; r < 4; ++r) {
          float cr = __shfl(corr, g * 4 + r);
          o[qi][0][r] *= cr; o[qi][1][r] *= cr;
        }
        m_[qi] = mnew;
      }
      float rs = 0.f;
      int q = qi * 16 + l15;
      #pragma unroll
      for (int ti = 0; ti < 4; ++ti) {
        ushort pb[4];
        #pragma unroll
        for (int r = 0; r < 4; ++r) {
          float p = exp2f((s[ti][qi][r] - m_[qi]) * sc);
          rs += p;
          pb[r] = f2bf(p);
        }
        int sw = (ti * 2 + (g >> 1)) ^ (q & 7);
        uint2 val;
        val.x = (unsigned)pb[0] | ((unsigned)pb[1] << 16);
        val.y = (unsigned)pb[2] | ((unsigned)pb[3] << 16);
        *(uint2*)&Ps[w][q * 64 + sw * 8 + (g & 1) * 4] = val;
      }
      rs += __shfl_xor(rs, 16);
      rs += __shfl_xor(rs, 32);
      l_[qi] += rs;
    }

    bf16x8 pa[2][2], vb[2][2];
    #pragma unroll
    for (int mi = 0; mi < 2; ++mi)
      #pragma unroll
      for (int ks = 0; ks < 2; ++ks) {
        int q = mi * 16 + l15;
        pa[mi][ks] = *(const bf16x8*)&Ps[w][q * 64 + (((ks * 4 + g) ^ (q & 7)) * 8)];
      }
    #pragma unroll
    for (int ks = 0; ks < 2; ++ks)
      #pragma unroll
      for (int di = 0; di < 2; ++di) {
        int d = di * 16 + l15;
        vb[ks][di] = *(const bf16x8*)&Vt[cur][d * 64 + (((ks * 4 + g) ^ (d & 7)) * 8)];
      }
    __builtin_amdgcn_s_setprio(1);
    #pragma unroll
    for (int mi = 0; mi < 2; ++mi)
      #pragma unroll
      for (int di = 0; di < 2; ++di)
        #pragma unroll
        for (int ks = 0; ks < 2; ++ks)
          o[mi][di] = __builtin_amdgcn_mfma_f32_16x16x32_bf16(
              pa[mi][ks], vb[ks][di], o[mi][di], 0, 0, 0);
    __builtin_amdgcn_s_setprio(0);
    __syncthreads();
    cur ^= 1;
  }

  // store partials: unnormalized O (bf16) + m/l (f32, one copy per q-row)
  #pragma unroll
  for (int qi = 0; qi < 2; ++qi) {
    if (g == 0) {
      size_t qrow = (size_t)b * SEQ + q0 + wq0 + qi * 16 + l15;
      size_t idx = ((size_t)kvs * NROWS + qrow) * 16 + h * 2;
      pml[idx] = m_[qi];
      pml[idx + 1] = l_[qi];
    }
    #pragma unroll
    for (int r = 0; r < 4; ++r) {
      size_t row = (size_t)b * SEQ + q0 + wq0 + qi * 16 + g * 4 + r;
      #pragma unroll
      for (int di = 0; di < 2; ++di) {
        int col = h * 32 + di * 16 + l15;
        po[(size_t)kvs * 2097152 + row * 256 + col] = f2bf(o[qi][di][r]);
      }
    }
  }
}

// -------- 4b. combine the four KV quarters --------
__global__ __launch_bounds__(256) void attn_combine_kernel(
    const ushort* __restrict__ po, const float* __restrict__ pml,
    ushort* __restrict__ att)
{
  const float sc = 0.25507964954389985f;
  int row = blockIdx.x, c = threadIdx.x, h = c >> 5;
  float mi[4], li[4];
  float m = -1e30f;
  #pragma unroll
  for (int p = 0; p < 4; ++p) {
    size_t idx = ((size_t)p * NROWS + row) * 16 + h * 2;
    mi[p] = pml[idx]; li[p] = pml[idx + 1];
    m = fmaxf(m, mi[p]);
  }
  float num = 0.f, den = 0.f;
  #pragma unroll
  for (int p = 0; p < 4; ++p) {
    float wgt = exp2f((mi[p] - m) * sc);
    num += wgt * bf2f(po[(size_t)p * 2097152 + (size_t)row * 256 + c]);
    den += wgt * li[p];
  }
  att[(size_t)row * 256 + swz(c, row & 7)] = f2bf(num / den);
}

extern "C" void kernel_launch(void* const* d_in, const int* in_sizes, int n_in,
                              void* d_out, int out_size, void* d_ws, size_t ws_size,
                              hipStream_t stream)
{
  const float* x    = (const float*)d_in[0];
  const float* y    = (const float*)d_in[1];
  const float* Wqkv = (const float*)d_in[3];
  const float* bqkv = (const float*)d_in[4];
  const float* Wo   = (const float*)d_in[5];
  const float* bo   = (const float*)d_in[6];
  const float* W1   = (const float*)d_in[7];
  const float* b1   = (const float*)d_in[8];
  const float* W2   = (const float*)d_in[9];
  const float* b2   = (const float*)d_in[10];
  const float* g1   = (const float*)d_in[11];
  const float* be1  = (const float*)d_in[12];
  const float* g2   = (const float*)d_in[13];
  const float* be2  = (const float*)d_in[14];

  float* ws = (float*)d_ws;
  ushort* f_bf   = (ushort*)(ws);                 // [0, 1M) floats, swizzled bf16
  ushort* qkv_bf = (ushort*)(ws + 1048576);       // [1M, 4M) linear
  ushort* att_bf = (ushort*)(ws + 4194304);       // [4M, 5M) swizzled
  ushort* f1_bf  = (ushort*)(ws + 5242880);       // [5M, 6M) swizzled
  ushort* h_bf   = (ushort*)(ws + 6291456);       // [6M, 8M) swizzled
  ushort* vt_g   = (ushort*)(ws + 8388608);       // [8M, 9M)
  ushort* po     = (ushort*)(ws + 9437184);       // [9M, 13M) 4 planes x 2M bf16
  float*  pml    = ws + 13631488;                 // [13M, 13.5M)
  float*  pos    = ws + 14680064;                 // [14M, 14.25M)
  ushort* wq_bf  = (ushort*)(ws + 15728640);
  ushort* wo_bf  = wq_bf + 196608;
  ushort* w1_bf  = wo_bf + 65536;
  ushort* w2_bf  = w1_bf + 262144;

  prep_kernel<<<1024, 256, 0, stream>>>(Wqkv, Wo, W1, W2, wq_bf, wo_bf, w1_bf, w2_bf, pos);
  build_f_kernel<<<512, 256, 0, stream>>>(x, y, pos, f_bf);
  gemm_mfma_kernel<64, 1, 0><<<dim3(6, 128), 256, 0, stream>>>(f_bf, wq_bf, bqkv, qkv_bf, NROWS, 768, 256);
  vtrans_kernel<<<dim3(16, 64), 256, 0, stream>>>(qkv_bf, vt_g);
  attn_mfma_kernel<<<dim3(32, 8, 8), 256, 0, stream>>>(qkv_bf, vt_g, po, pml);
  attn_combine_kernel<<<8192, 256, 0, stream>>>(po, pml, att_bf);
  gemm_ln_kernel<0><<<256, 256, 0, stream>>>(att_bf, wo_bf, bo, f_bf, g1, be1, nullptr, f1_bf, 256);
  gemm_mfma_kernel<128, 2, 1><<<dim3(8, 64), 256, 0, stream>>>(f1_bf, w1_bf, b1, h_bf, NROWS, 1024, 256);
  gemm_ln_kernel<1><<<256, 256, 0, stream>>>(h_bf, w2_bf, b2, f1_bf, g2, be2, (float*)d_out, nullptr, 1024);
}

// Round 7
// 108.204 us; speedup vs baseline: 5.6177x; 1.0495x over previous
//
#include <hip/hip_runtime.h>

typedef __attribute__((ext_vector_type(8))) short bf16x8;
typedef __attribute__((ext_vector_type(4))) float f32x4;

#define D_MODEL 256
#define SEQ     1024
#define NROWS   8192

__device__ __forceinline__ ushort f2bf(float f) {
  unsigned u = __float_as_uint(f);
  unsigned r = (u + 0x7FFFu + ((u >> 16) & 1u)) >> 16;
  return (ushort)r;
}
__device__ __forceinline__ float bf2f(ushort b) {
  return __uint_as_float(((unsigned)b) << 16);
}

// async global->LDS, 16B per lane; dst = wave-uniform base + lane*16
__device__ __forceinline__ void gld_lds16(const void* g, void* l) {
  __builtin_amdgcn_global_load_lds(
      (const __attribute__((address_space(1))) void*)g,
      (__attribute__((address_space(3))) void*)l, 16, 0, 0);
}

// XOR-swizzle of 8-element blocks within 64-col groups
__device__ __forceinline__ int swz(int col, int row7) {
  return (col & ~63) | ((((col >> 3) & 7) ^ row7) << 3) | (col & 7);
}

// -------- 0. prep: weights fp32 -> bf16 pre-swizzled  +  pos table --------
__global__ __launch_bounds__(256) void prep_kernel(
    const float* __restrict__ a, const float* __restrict__ b,
    const float* __restrict__ c, const float* __restrict__ d,
    ushort* __restrict__ oa, ushort* __restrict__ ob,
    ushort* __restrict__ oc, ushort* __restrict__ od,
    float* __restrict__ pos)
{
  int i = blockIdx.x * 256 + threadIdx.x;  // 262144 total
  if (i < 196608) { int r = i >> 8, k = i & 255; oa[(r << 8) + swz(k, r & 7)] = f2bf(a[i]); }
  if (i <  65536) { int r = i >> 8, k = i & 255; ob[(r << 8) + swz(k, r & 7)] = f2bf(b[i]); }
  { int r = i >> 8,  k = i & 255;  oc[(r << 8)  + swz(k, r & 7)] = f2bf(c[i]); }
  { int r = i >> 10, k = i & 1023; od[(r << 10) + swz(k, r & 7)] = f2bf(d[i]); }
  // pos
  {
    int s = i >> 8, cc = i & 255;
    int hh = s >> 5, w = s & 31;
    const float sc = 6.28318530717958647692f / (32.0f + 1e-6f);
    float e;
    int c2 = cc;
    if (c2 < 128) { e = (float)(hh + 1) * sc; }
    else          { e = (float)(w  + 1) * sc; c2 -= 128; }
    int j = c2 >> 1;
    float arg = e * exp2f((float)j * -0.20762050593046014f);  // 10000^(-j/64)
    pos[i] = (c2 & 1) ? cosf(arg) : sinf(arg);
  }
}

// -------- 1. f_bf[row][swz(c)] = transpose(x/y) + 0.1*pos  (bf16 only) --------
__global__ __launch_bounds__(256) void build_f_kernel(
    const float* __restrict__ x, const float* __restrict__ y,
    const float* __restrict__ pos, ushort* __restrict__ fb)
{
  __shared__ float T[64][65];
  int bx = blockIdx.x;                    // 8b * 16st * 4ct = 512
  int b = bx >> 6, st = (bx >> 2) & 15, ct = bx & 3;
  const float* src = (b < 4) ? x : y;
  int bb = b & 3;
  int tid = threadIdx.x;
  {
    int sl = tid & 63, c4 = tid >> 6;
    int s = st * 64 + sl;
    #pragma unroll
    for (int k = 0; k < 16; ++k) {
      int cl = c4 * 16 + k;
      T[cl][sl] = src[((size_t)((bb << 8) + ct * 64 + cl) << 10) + s];
    }
  }
  __syncthreads();
  {
    int cl = tid & 63, s4 = tid >> 6;
    int c = ct * 64 + cl;
    #pragma unroll
    for (int k = 0; k < 16; ++k) {
      int sl = s4 * 16 + k;
      int s = st * 64 + sl;
      float v = T[cl][sl] + 0.1f * pos[s * 256 + c];
      size_t row = (size_t)b * 1024 + s;
      fb[row * 256 + swz(c, s & 7)] = f2bf(v);
    }
  }
}

// -------- 2. MFMA GEMM (BN=128), global_load_lds, pre-swizzled inputs --------
// OUT_MODE: 2 = bf16 swizzled, 3 = qkv fused (Q,K linear; V -> vt transposed)
template<int BM, int OUT_MODE, int RELU>
__global__ __launch_bounds__(256) void gemm_mfma_kernel(
    const ushort* __restrict__ A, const ushort* __restrict__ B,
    const float* __restrict__ bias, void* __restrict__ Cout,
    ushort* __restrict__ Vout, int M, int N, int K)
{
  constexpr int MI = BM / 32;
  __shared__ ushort Asw[BM * 64];
  __shared__ ushort Bsw[128 * 64];
  const int tid = threadIdx.x, lane = tid & 63, w = tid >> 6;
  const int m0 = blockIdx.y * BM, n0 = blockIdx.x * 128;
  const int wm0 = (w & 1) * (BM / 2), wn0 = (w >> 1) * 64;
  const int l15 = lane & 15, g = lane >> 4;
  const int r8 = lane >> 3, s8 = lane & 7;
  f32x4 acc[MI][4];
  #pragma unroll
  for (int i = 0; i < MI; ++i)
    #pragma unroll
    for (int j = 0; j < 4; ++j) acc[i][j] = (f32x4){0.f, 0.f, 0.f, 0.f};

  for (int kt = 0; kt < K; kt += 64) {
    __syncthreads();
    #pragma unroll
    for (int i = 0; i < BM / 32; ++i) {
      int row0 = w * (BM / 4) + i * 8;
      gld_lds16(A + (size_t)(m0 + row0 + r8) * K + kt + s8 * 8, &Asw[row0 * 64]);
    }
    #pragma unroll
    for (int i = 0; i < 4; ++i) {
      int row0 = w * 32 + i * 8;
      gld_lds16(B + (size_t)(n0 + row0 + r8) * K + kt + s8 * 8, &Bsw[row0 * 64]);
    }
    __syncthreads();
    #pragma unroll
    for (int ks = 0; ks < 2; ++ks) {
      bf16x8 af[MI], bfr[4];
      #pragma unroll
      for (int i = 0; i < MI; ++i) {
        int ra = wm0 + i * 16 + l15;
        af[i] = *(const bf16x8*)&Asw[ra * 64 + (((ks * 4 + g) ^ (ra & 7)) * 8)];
      }
      #pragma unroll
      for (int i = 0; i < 4; ++i) {
        int rb = wn0 + i * 16 + l15;
        bfr[i] = *(const bf16x8*)&Bsw[rb * 64 + (((ks * 4 + g) ^ (rb & 7)) * 8)];
      }
      __builtin_amdgcn_s_setprio(1);
      #pragma unroll
      for (int mi = 0; mi < MI; ++mi)
        #pragma unroll
        for (int ni = 0; ni < 4; ++ni)
          acc[mi][ni] = __builtin_amdgcn_mfma_f32_16x16x32_bf16(
              af[mi], bfr[ni], acc[mi][ni], 0, 0, 0);
      __builtin_amdgcn_s_setprio(0);
    }
  }

  float bv[4];
  #pragma unroll
  for (int ni = 0; ni < 4; ++ni) bv[ni] = bias[n0 + wn0 + ni * 16 + l15];
  #pragma unroll
  for (int mi = 0; mi < MI; ++mi)
    #pragma unroll
    for (int ni = 0; ni < 4; ++ni) {
      float v4[4];
      #pragma unroll
      for (int r = 0; r < 4; ++r) {
        float v = acc[mi][ni][r] + bv[ni];
        if (RELU) v = fmaxf(v, 0.0f);
        v4[r] = v;
      }
      int n = n0 + wn0 + ni * 16 + l15;
      int mb = m0 + wm0 + mi * 16 + g * 4;       // first of 4 consecutive rows
      if (OUT_MODE == 3 && n >= 512) {
        // V column -> vt[bh][d][t] with 8-block swizzle on t within 64-groups
        int d = (n - 512) & 31, hh = (n - 512) >> 5;
        int bb = mb >> 10, t0 = mb & 1023;
        uint2 val;
        val.x = (unsigned)f2bf(v4[0]) | ((unsigned)f2bf(v4[1]) << 16);
        val.y = (unsigned)f2bf(v4[2]) | ((unsigned)f2bf(v4[3]) << 16);
        size_t idx = ((size_t)(bb * 8 + hh) * 32 + d) * 1024 + (t0 & ~63)
                   + ((((t0 >> 3) & 7) ^ (d & 7)) * 8) + (t0 & 7);
        *(uint2*)&Vout[idx] = val;
      } else {
        #pragma unroll
        for (int r = 0; r < 4; ++r) {
          size_t m = mb + r;
          if (OUT_MODE == 3) ((ushort*)Cout)[m * N + n] = f2bf(v4[r]);
          else               ((ushort*)Cout)[m * N + swz(n, (int)(m & 7))] = f2bf(v4[r]);
        }
      }
    }
}

// -------- 2b. GEMM (BM=32, BN=256=N) + fused residual(bf16 swz) + LayerNorm --------
// TRANS_OUT=0: outb = bf16 swizzled.  TRANS_OUT=1: transposed f32 d_out.
template<int TRANS_OUT>
__global__ __launch_bounds__(256) void gemm_ln_kernel(
    const ushort* __restrict__ A, const ushort* __restrict__ B,
    const float* __restrict__ bias, const ushort* __restrict__ R,
    const float* __restrict__ gamma, const float* __restrict__ beta,
    float* __restrict__ out, ushort* __restrict__ outb, int K)
{
  __shared__ ushort Asw[32 * 64];
  __shared__ ushort Bsw[256 * 64];
  __shared__ float red[4][32][2];
  const int tid = threadIdx.x, lane = tid & 63, w = tid >> 6;
  const int l15 = lane & 15, g4 = lane >> 4;
  const int r8 = lane >> 3, s8 = lane & 7;
  const int m0 = blockIdx.x * 32;
  const int wn0 = w * 64;
  f32x4 acc[2][4];
  #pragma unroll
  for (int i = 0; i < 2; ++i)
    #pragma unroll
    for (int j = 0; j < 4; ++j) acc[i][j] = (f32x4){0.f, 0.f, 0.f, 0.f};

  for (int kt = 0; kt < K; kt += 64) {
    __syncthreads();
    gld_lds16(A + (size_t)(m0 + w * 8 + r8) * K + kt + s8 * 8, &Asw[(w * 8) * 64]);
    #pragma unroll
    for (int i = 0; i < 8; ++i) {
      int row0 = w * 64 + i * 8;
      gld_lds16(B + (size_t)(row0 + r8) * K + kt + s8 * 8, &Bsw[row0 * 64]);
    }
    __syncthreads();
    #pragma unroll
    for (int ks = 0; ks < 2; ++ks) {
      bf16x8 af[2], bfr[4];
      #pragma unroll
      for (int mi = 0; mi < 2; ++mi) {
        int ra = mi * 16 + l15;
        af[mi] = *(const bf16x8*)&Asw[ra * 64 + (((ks * 4 + g4) ^ (ra & 7)) * 8)];
      }
      #pragma unroll
      for (int ni = 0; ni < 4; ++ni) {
        int rb = wn0 + ni * 16 + l15;
        bfr[ni] = *(const bf16x8*)&Bsw[rb * 64 + (((ks * 4 + g4) ^ (rb & 7)) * 8)];
      }
      __builtin_amdgcn_s_setprio(1);
      #pragma unroll
      for (int mi = 0; mi < 2; ++mi)
        #pragma unroll
        for (int ni = 0; ni < 4; ++ni)
          acc[mi][ni] = __builtin_amdgcn_mfma_f32_16x16x32_bf16(
              af[mi], bfr[ni], acc[mi][ni], 0, 0, 0);
      __builtin_amdgcn_s_setprio(0);
    }
  }

  float bv[4], gv[4], bev[4];
  #pragma unroll
  for (int ni = 0; ni < 4; ++ni) {
    int n = wn0 + ni * 16 + l15;
    bv[ni] = bias[n]; gv[ni] = gamma[n]; bev[ni] = beta[n];
  }
  float s1[2][4], s2[2][4];
  #pragma unroll
  for (int mi = 0; mi < 2; ++mi)
    #pragma unroll
    for (int r = 0; r < 4; ++r) { s1[mi][r] = 0.f; s2[mi][r] = 0.f; }
  #pragma unroll
  for (int mi = 0; mi < 2; ++mi)
    #pragma unroll
    for (int ni = 0; ni < 4; ++ni)
      #pragma unroll
      for (int r = 0; r < 4; ++r) {
        int row = m0 + mi * 16 + g4 * 4 + r;
        int col = wn0 + ni * 16 + l15;
        float v = acc[mi][ni][r] + bv[ni] + bf2f(R[(size_t)row * 256 + swz(col, row & 7)]);
        acc[mi][ni][r] = v;
        s1[mi][r] += v;
        s2[mi][r] += v * v;
      }
  #pragma unroll
  for (int mi = 0; mi < 2; ++mi)
    #pragma unroll
    for (int r = 0; r < 4; ++r) {
      #pragma unroll
      for (int d = 1; d < 16; d <<= 1) {
        s1[mi][r] += __shfl_xor(s1[mi][r], d);
        s2[mi][r] += __shfl_xor(s2[mi][r], d);
      }
    }
  if (l15 == 0) {
    #pragma unroll
    for (int mi = 0; mi < 2; ++mi)
      #pragma unroll
      for (int r = 0; r < 4; ++r) {
        int rl = mi * 16 + g4 * 4 + r;
        red[w][rl][0] = s1[mi][r];
        red[w][rl][1] = s2[mi][r];
      }
  }
  __syncthreads();
  #pragma unroll
  for (int mi = 0; mi < 2; ++mi)
    #pragma unroll
    for (int r = 0; r < 4; ++r) {
      int rl = mi * 16 + g4 * 4 + r;
      float t1 = red[0][rl][0] + red[1][rl][0] + red[2][rl][0] + red[3][rl][0];
      float t2 = red[0][rl][1] + red[1][rl][1] + red[2][rl][1] + red[3][rl][1];
      float mu = t1 * (1.0f / 256.0f);
      float var = t2 * (1.0f / 256.0f) - mu * mu;
      float rstd = rsqrtf(var + 1e-5f);
      int row = m0 + rl;
      #pragma unroll
      for (int ni = 0; ni < 4; ++ni) {
        int col = wn0 + ni * 16 + l15;
        float res = (acc[mi][ni][r] - mu) * rstd * gv[ni] + bev[ni];
        if (!TRANS_OUT) {
          outb[(size_t)row * 256 + swz(col, row & 7)] = f2bf(res);
        } else {
          int b = row >> 10, sq = row & 1023;
          size_t dst;
          if (b < 4) dst = ((size_t)((b << 8) + col) << 10) + sq;
          else       dst = (size_t)1048576 + ((size_t)(((b - 4) << 8) + col) << 10) + sq;
          out[dst] = res;
        }
      }
    }
}

// -------- 3. MFMA flash attention: 64 q-rows/block, full KV sweep, direct out --------
__global__ __launch_bounds__(256) void attn_mfma_kernel(
    const ushort* __restrict__ qkv, const ushort* __restrict__ vtg,
    ushort* __restrict__ att)
{
  __shared__ ushort Ks[2][64 * 32];
  __shared__ ushort Vt[2][32 * 64];
  __shared__ ushort Ps[4][16 * 72];     // 72-stride: banks spread by q
  const int tid = threadIdx.x, lane = tid & 63, w = tid >> 6;
  const int l15 = lane & 15, g = lane >> 4;
  const int qt = blockIdx.x, h = blockIdx.y, b = blockIdx.z;
  const size_t base = (size_t)b * SEQ * 768;
  const int q0 = qt * 64;
  const int bh = b * 8 + h;
  const float sc = 0.25507964954389985f;   // (1/sqrt(32)) * log2(e)

  // Q fragment: wave w owns q rows q0 + w*16 + l15
  bf16x8 qf = *(const bf16x8*)&qkv[base + (size_t)(q0 + w * 16 + l15) * 768 + h * 32 + g * 8];

  // stage tile 0 (K source block-swizzled so LDS[r][blk] = g[r][blk^(r&3)])
  {
    int r = lane >> 2, qb = lane & 3;
    gld_lds16(qkv + base + (size_t)(w * 16 + r) * 768 + 256 + h * 32 + ((qb ^ (r & 3)) * 8),
              &Ks[0][w * 16 * 32]);
    gld_lds16(vtg + ((size_t)bh * 32 + w * 8 + (lane >> 3)) * 1024 + (lane & 7) * 8,
              &Vt[0][w * 8 * 64]);
  }
  __syncthreads();

  float m_ = -1e30f, l_ = 0.f;
  f32x4 o[2];
  o[0] = (f32x4){0.f, 0.f, 0.f, 0.f};
  o[1] = (f32x4){0.f, 0.f, 0.f, 0.f};
  const f32x4 zero = (f32x4){0.f, 0.f, 0.f, 0.f};

  int cur = 0;
  for (int t = 0; t < 16; ++t) {
    if (t < 15) {                          // prefetch next K/V tile
      int nkv = t * 64 + 64;
      int r = lane >> 2, qb = lane & 3;
      gld_lds16(qkv + base + (size_t)(nkv + w * 16 + r) * 768 + 256 + h * 32 + ((qb ^ (r & 3)) * 8),
                &Ks[cur ^ 1][w * 16 * 32]);
      gld_lds16(vtg + ((size_t)bh * 32 + w * 8 + (lane >> 3)) * 1024 + nkv + (lane & 7) * 8,
                &Vt[cur ^ 1][w * 8 * 64]);
    }
    // S^T = K . Q^T : lane owns q = l15, t = ti*16 + g*4 + r
    bf16x8 kf[4];
    #pragma unroll
    for (int ti = 0; ti < 4; ++ti) {
      int row = ti * 16 + l15;
      kf[ti] = *(const bf16x8*)&Ks[cur][row * 32 + ((g ^ (row & 3)) * 8)];
    }
    f32x4 s[4];
    __builtin_amdgcn_s_setprio(1);
    #pragma unroll
    for (int ti = 0; ti < 4; ++ti)
      s[ti] = __builtin_amdgcn_mfma_f32_16x16x32_bf16(kf[ti], qf, zero, 0, 0, 0);
    __builtin_amdgcn_s_setprio(0);

    // online softmax (q = l15)
    {
      float mx = s[0][0];
      #pragma unroll
      for (int ti = 0; ti < 4; ++ti)
        #pragma unroll
        for (int r = 0; r < 4; ++r) if (ti + r) mx = fmaxf(mx, s[ti][r]);
      mx = fmaxf(mx, __shfl_xor(mx, 16));
      mx = fmaxf(mx, __shfl_xor(mx, 32));
      if (!__all(mx <= m_ + 31.36f)) {     // defer-max: 8/sc raw-score units
        float mnew = fmaxf(m_, mx);
        float corr = exp2f((m_ - mnew) * sc);
        l_ *= corr;
        #pragma unroll
        for (int r = 0; r < 4; ++r) {
          float cr = __shfl(corr, g * 4 + r);
          o[0][r] *= cr; o[1][r] *= cr;
        }
        m_ = mnew;
      }
      float rs = 0.f;
      int q = l15;
      #pragma unroll
      for (int ti = 0; ti < 4; ++ti) {
        ushort pb[4];
        #pragma unroll
        for (int r = 0; r < 4; ++r) {
          float p = exp2f((s[ti][r] - m_) * sc);
          rs += p;
          pb[r] = f2bf(p);
        }
        int sw = (ti * 2 + (g >> 1)) ^ (q & 7);
        uint2 val;
        val.x = (unsigned)pb[0] | ((unsigned)pb[1] << 16);
        val.y = (unsigned)pb[2] | ((unsigned)pb[3] << 16);
        *(uint2*)&Ps[w][q * 72 + sw * 8 + (g & 1) * 4] = val;
      }
      rs += __shfl_xor(rs, 16);
      rs += __shfl_xor(rs, 32);
      l_ += rs;
    }

    // O += P . V
    bf16x8 pa[2], vb[2][2];
    #pragma unroll
    for (int ks = 0; ks < 2; ++ks)
      pa[ks] = *(const bf16x8*)&Ps[w][l15 * 72 + (((ks * 4 + g) ^ (l15 & 7)) * 8)];
    #pragma unroll
    for (int ks = 0; ks < 2; ++ks)
      #pragma unroll
      for (int di = 0; di < 2; ++di) {
        int d = di * 16 + l15;
        vb[ks][di] = *(const bf16x8*)&Vt[cur][d * 64 + (((ks * 4 + g) ^ (d & 7)) * 8)];
      }
    __builtin_amdgcn_s_setprio(1);
    #pragma unroll
    for (int di = 0; di < 2; ++di)
      #pragma unroll
      for (int ks = 0; ks < 2; ++ks)
        o[di] = __builtin_amdgcn_mfma_f32_16x16x32_bf16(pa[ks], vb[ks][di], o[di], 0, 0, 0);
    __builtin_amdgcn_s_setprio(0);
    __syncthreads();
    cur ^= 1;
  }

  // normalized store, swizzled bf16 [8192][256]
  #pragma unroll
  for (int r = 0; r < 4; ++r) {
    float lr = __shfl(l_, g * 4 + r);
    float inv = 1.0f / lr;
    size_t row = (size_t)b * SEQ + q0 + w * 16 + g * 4 + r;
    int rw7 = (g * 4 + r) & 7;
    #pragma unroll
    for (int di = 0; di < 2; ++di) {
      int col = h * 32 + di * 16 + l15;
      att[row * 256 + swz(col, rw7)] = f2bf(o[di][r] * inv);
    }
  }
}

extern "C" void kernel_launch(void* const* d_in, const int* in_sizes, int n_in,
                              void* d_out, int out_size, void* d_ws, size_t ws_size,
                              hipStream_t stream)
{
  const float* x    = (const float*)d_in[0];
  const float* y    = (const float*)d_in[1];
  const float* Wqkv = (const float*)d_in[3];
  const float* bqkv = (const float*)d_in[4];
  const float* Wo   = (const float*)d_in[5];
  const float* bo   = (const float*)d_in[6];
  const float* W1   = (const float*)d_in[7];
  const float* b1   = (const float*)d_in[8];
  const float* W2   = (const float*)d_in[9];
  const float* b2   = (const float*)d_in[10];
  const float* g1   = (const float*)d_in[11];
  const float* be1  = (const float*)d_in[12];
  const float* g2   = (const float*)d_in[13];
  const float* be2  = (const float*)d_in[14];

  float* ws = (float*)d_ws;
  ushort* f_bf   = (ushort*)(ws);                 // [0, 1M) floats: swizzled bf16
  ushort* qkv_bf = (ushort*)(ws + 1048576);       // [1M, 4M): Q,K linear (V cols unused)
  ushort* vt_g   = (ushort*)(ws + 4194304);       // [4M, 5M): vt[bh][32][1024] swizzled
  ushort* att_bf = (ushort*)(ws + 5242880);       // [5M, 6M) swizzled
  ushort* f1_bf  = (ushort*)(ws + 6291456);       // [6M, 7M) swizzled
  ushort* h_bf   = (ushort*)(ws + 7340032);       // [7M, 11M) swizzled
  float*  pos    = ws + 11534336;                 // [11M, 11.25M)
  ushort* wq_bf  = (ushort*)(ws + 12582912);
  ushort* wo_bf  = wq_bf + 196608;
  ushort* w1_bf  = wo_bf + 65536;
  ushort* w2_bf  = w1_bf + 262144;

  prep_kernel<<<1024, 256, 0, stream>>>(Wqkv, Wo, W1, W2, wq_bf, wo_bf, w1_bf, w2_bf, pos);
  build_f_kernel<<<512, 256, 0, stream>>>(x, y, pos, f_bf);
  gemm_mfma_kernel<64, 3, 0><<<dim3(6, 128), 256, 0, stream>>>(
      f_bf, wq_bf, bqkv, qkv_bf, vt_g, NROWS, 768, 256);
  attn_mfma_kernel<<<dim3(16, 8, 8), 256, 0, stream>>>(qkv_bf, vt_g, att_bf);
  gemm_ln_kernel<0><<<256, 256, 0, stream>>>(att_bf, wo_bf, bo, f_bf, g1, be1, nullptr, f1_bf, 256);
  gemm_mfma_kernel<128, 2, 1><<<dim3(8, 64), 256, 0, stream>>>(
      f1_bf, w1_bf, b1, h_bf, nullptr, NROWS, 1024, 256);
  gemm_ln_kernel<1><<<256, 256, 0, stream>>>(h_bf, w2_bf, b2, f1_bf, g2, be2, (float*)d_out, nullptr, 1024);
}

// Round 8
// 106.151 us; speedup vs baseline: 5.7263x; 1.0193x over previous
//
#include <hip/hip_runtime.h>

typedef __attribute__((ext_vector_type(8))) short bf16x8;
typedef __attribute__((ext_vector_type(4))) float f32x4;

#define D_MODEL 256
#define SEQ     1024
#define NROWS   8192

__device__ __forceinline__ ushort f2bf(float f) {
  unsigned u = __float_as_uint(f);
  unsigned r = (u + 0x7FFFu + ((u >> 16) & 1u)) >> 16;
  return (ushort)r;
}
__device__ __forceinline__ float bf2f(ushort b) {
  return __uint_as_float(((unsigned)b) << 16);
}

// async global->LDS, 16B per lane; dst = wave-uniform base + lane*16
__device__ __forceinline__ void gld_lds16(const void* g, void* l) {
  __builtin_amdgcn_global_load_lds(
      (const __attribute__((address_space(1))) void*)g,
      (__attribute__((address_space(3))) void*)l, 16, 0, 0);
}

// XOR-swizzle of 8-element blocks within 64-col groups
__device__ __forceinline__ int swz(int col, int row7) {
  return (col & ~63) | ((((col >> 3) & 7) ^ row7) << 3) | (col & 7);
}

// -------- 0. prep: weights fp32 -> bf16 pre-swizzled  +  pos table --------
__global__ __launch_bounds__(256) void prep_kernel(
    const float* __restrict__ a, const float* __restrict__ b,
    const float* __restrict__ c, const float* __restrict__ d,
    ushort* __restrict__ oa, ushort* __restrict__ ob,
    ushort* __restrict__ oc, ushort* __restrict__ od,
    float* __restrict__ pos)
{
  int i = blockIdx.x * 256 + threadIdx.x;  // 262144 total
  if (i < 196608) { int r = i >> 8, k = i & 255; oa[(r << 8) + swz(k, r & 7)] = f2bf(a[i]); }
  if (i <  65536) { int r = i >> 8, k = i & 255; ob[(r << 8) + swz(k, r & 7)] = f2bf(b[i]); }
  { int r = i >> 8,  k = i & 255;  oc[(r << 8)  + swz(k, r & 7)] = f2bf(c[i]); }
  { int r = i >> 10, k = i & 1023; od[(r << 10) + swz(k, r & 7)] = f2bf(d[i]); }
  // pos
  {
    int s = i >> 8, cc = i & 255;
    int hh = s >> 5, w = s & 31;
    const float sc = 6.28318530717958647692f / (32.0f + 1e-6f);
    float e;
    int c2 = cc;
    if (c2 < 128) { e = (float)(hh + 1) * sc; }
    else          { e = (float)(w  + 1) * sc; c2 -= 128; }
    int j = c2 >> 1;
    float arg = e * exp2f((float)j * -0.20762050593046014f);  // 10000^(-j/64)
    pos[i] = (c2 & 1) ? cosf(arg) : sinf(arg);
  }
}

// -------- 1. f_bf[row][swz(c)] = transpose(x/y) + 0.1*pos  (bf16 only) --------
__global__ __launch_bounds__(256) void build_f_kernel(
    const float* __restrict__ x, const float* __restrict__ y,
    const float* __restrict__ pos, ushort* __restrict__ fb)
{
  __shared__ float T[64][65];
  int bx = blockIdx.x;                    // 8b * 16st * 4ct = 512
  int b = bx >> 6, st = (bx >> 2) & 15, ct = bx & 3;
  const float* src = (b < 4) ? x : y;
  int bb = b & 3;
  int tid = threadIdx.x;
  {
    int sl = tid & 63, c4 = tid >> 6;
    int s = st * 64 + sl;
    #pragma unroll
    for (int k = 0; k < 16; ++k) {
      int cl = c4 * 16 + k;
      T[cl][sl] = src[((size_t)((bb << 8) + ct * 64 + cl) << 10) + s];
    }
  }
  __syncthreads();
  {
    int cl = tid & 63, s4 = tid >> 6;
    int c = ct * 64 + cl;
    #pragma unroll
    for (int k = 0; k < 16; ++k) {
      int sl = s4 * 16 + k;
      int s = st * 64 + sl;
      float v = T[cl][sl] + 0.1f * pos[s * 256 + c];
      size_t row = (size_t)b * 1024 + s;
      fb[row * 256 + swz(c, s & 7)] = f2bf(v);
    }
  }
}

// -------- 2. MFMA GEMM (BN=128), global_load_lds, pre-swizzled inputs --------
// OUT_MODE: 2 = bf16 swizzled, 3 = qkv fused (Q,K linear; V -> vt transposed)
template<int BM, int OUT_MODE, int RELU>
__global__ __launch_bounds__(256) void gemm_mfma_kernel(
    const ushort* __restrict__ A, const ushort* __restrict__ B,
    const float* __restrict__ bias, void* __restrict__ Cout,
    ushort* __restrict__ Vout, int M, int N, int K)
{
  constexpr int MI = BM / 32;
  __shared__ ushort Asw[BM * 64];
  __shared__ ushort Bsw[128 * 64];
  const int tid = threadIdx.x, lane = tid & 63, w = tid >> 6;
  const int m0 = blockIdx.y * BM, n0 = blockIdx.x * 128;
  const int wm0 = (w & 1) * (BM / 2), wn0 = (w >> 1) * 64;
  const int l15 = lane & 15, g = lane >> 4;
  const int r8 = lane >> 3, s8 = lane & 7;
  f32x4 acc[MI][4];
  #pragma unroll
  for (int i = 0; i < MI; ++i)
    #pragma unroll
    for (int j = 0; j < 4; ++j) acc[i][j] = (f32x4){0.f, 0.f, 0.f, 0.f};

  for (int kt = 0; kt < K; kt += 64) {
    __syncthreads();
    #pragma unroll
    for (int i = 0; i < BM / 32; ++i) {
      int row0 = w * (BM / 4) + i * 8;
      gld_lds16(A + (size_t)(m0 + row0 + r8) * K + kt + s8 * 8, &Asw[row0 * 64]);
    }
    #pragma unroll
    for (int i = 0; i < 4; ++i) {
      int row0 = w * 32 + i * 8;
      gld_lds16(B + (size_t)(n0 + row0 + r8) * K + kt + s8 * 8, &Bsw[row0 * 64]);
    }
    __syncthreads();
    #pragma unroll
    for (int ks = 0; ks < 2; ++ks) {
      bf16x8 af[MI], bfr[4];
      #pragma unroll
      for (int i = 0; i < MI; ++i) {
        int ra = wm0 + i * 16 + l15;
        af[i] = *(const bf16x8*)&Asw[ra * 64 + (((ks * 4 + g) ^ (ra & 7)) * 8)];
      }
      #pragma unroll
      for (int i = 0; i < 4; ++i) {
        int rb = wn0 + i * 16 + l15;
        bfr[i] = *(const bf16x8*)&Bsw[rb * 64 + (((ks * 4 + g) ^ (rb & 7)) * 8)];
      }
      __builtin_amdgcn_s_setprio(1);
      #pragma unroll
      for (int mi = 0; mi < MI; ++mi)
        #pragma unroll
        for (int ni = 0; ni < 4; ++ni)
          acc[mi][ni] = __builtin_amdgcn_mfma_f32_16x16x32_bf16(
              af[mi], bfr[ni], acc[mi][ni], 0, 0, 0);
      __builtin_amdgcn_s_setprio(0);
    }
  }

  float bv[4];
  #pragma unroll
  for (int ni = 0; ni < 4; ++ni) bv[ni] = bias[n0 + wn0 + ni * 16 + l15];
  #pragma unroll
  for (int mi = 0; mi < MI; ++mi)
    #pragma unroll
    for (int ni = 0; ni < 4; ++ni) {
      float v4[4];
      #pragma unroll
      for (int r = 0; r < 4; ++r) {
        float v = acc[mi][ni][r] + bv[ni];
        if (RELU) v = fmaxf(v, 0.0f);
        v4[r] = v;
      }
      int n = n0 + wn0 + ni * 16 + l15;
      int mb = m0 + wm0 + mi * 16 + g * 4;       // first of 4 consecutive rows
      if (OUT_MODE == 3 && n >= 512) {
        // V column -> vt[bh][d][t] with 8-block swizzle on t within 64-groups
        int d = (n - 512) & 31, hh = (n - 512) >> 5;
        int bb = mb >> 10, t0 = mb & 1023;
        uint2 val;
        val.x = (unsigned)f2bf(v4[0]) | ((unsigned)f2bf(v4[1]) << 16);
        val.y = (unsigned)f2bf(v4[2]) | ((unsigned)f2bf(v4[3]) << 16);
        size_t idx = ((size_t)(bb * 8 + hh) * 32 + d) * 1024 + (t0 & ~63)
                   + ((((t0 >> 3) & 7) ^ (d & 7)) * 8) + (t0 & 7);
        *(uint2*)&Vout[idx] = val;
      } else {
        #pragma unroll
        for (int r = 0; r < 4; ++r) {
          size_t m = mb + r;
          if (OUT_MODE == 3) ((ushort*)Cout)[m * N + n] = f2bf(v4[r]);
          else               ((ushort*)Cout)[m * N + swz(n, (int)(m & 7))] = f2bf(v4[r]);
        }
      }
    }
}

// -------- 2b. GEMM (BM=32, BN=256=N) + fused residual(bf16 swz) + LayerNorm --------
// TRANS_OUT=0: outb = bf16 swizzled.  TRANS_OUT=1: transposed f32 d_out (coalesced via LDS).
template<int TRANS_OUT>
__global__ __launch_bounds__(256) void gemm_ln_kernel(
    const ushort* __restrict__ A, const ushort* __restrict__ B,
    const float* __restrict__ bias, const ushort* __restrict__ R,
    const float* __restrict__ gamma, const float* __restrict__ beta,
    float* __restrict__ out, ushort* __restrict__ outb, int K)
{
  __shared__ ushort Asw[32 * 64];
  __shared__ ushort Bsw[256 * 64];     // 32 KB; reused as f32 transpose tile in epilogue
  __shared__ float red[4][32][2];
  const int tid = threadIdx.x, lane = tid & 63, w = tid >> 6;
  const int l15 = lane & 15, g4 = lane >> 4;
  const int r8 = lane >> 3, s8 = lane & 7;
  const int m0 = blockIdx.x * 32;
  const int wn0 = w * 64;
  f32x4 acc[2][4];
  #pragma unroll
  for (int i = 0; i < 2; ++i)
    #pragma unroll
    for (int j = 0; j < 4; ++j) acc[i][j] = (f32x4){0.f, 0.f, 0.f, 0.f};

  for (int kt = 0; kt < K; kt += 64) {
    __syncthreads();
    gld_lds16(A + (size_t)(m0 + w * 8 + r8) * K + kt + s8 * 8, &Asw[(w * 8) * 64]);
    #pragma unroll
    for (int i = 0; i < 8; ++i) {
      int row0 = w * 64 + i * 8;
      gld_lds16(B + (size_t)(row0 + r8) * K + kt + s8 * 8, &Bsw[row0 * 64]);
    }
    __syncthreads();
    #pragma unroll
    for (int ks = 0; ks < 2; ++ks) {
      bf16x8 af[2], bfr[4];
      #pragma unroll
      for (int mi = 0; mi < 2; ++mi) {
        int ra = mi * 16 + l15;
        af[mi] = *(const bf16x8*)&Asw[ra * 64 + (((ks * 4 + g4) ^ (ra & 7)) * 8)];
      }
      #pragma unroll
      for (int ni = 0; ni < 4; ++ni) {
        int rb = wn0 + ni * 16 + l15;
        bfr[ni] = *(const bf16x8*)&Bsw[rb * 64 + (((ks * 4 + g4) ^ (rb & 7)) * 8)];
      }
      __builtin_amdgcn_s_setprio(1);
      #pragma unroll
      for (int mi = 0; mi < 2; ++mi)
        #pragma unroll
        for (int ni = 0; ni < 4; ++ni)
          acc[mi][ni] = __builtin_amdgcn_mfma_f32_16x16x32_bf16(
              af[mi], bfr[ni], acc[mi][ni], 0, 0, 0);
      __builtin_amdgcn_s_setprio(0);
    }
  }

  float bv[4], gv[4], bev[4];
  #pragma unroll
  for (int ni = 0; ni < 4; ++ni) {
    int n = wn0 + ni * 16 + l15;
    bv[ni] = bias[n]; gv[ni] = gamma[n]; bev[ni] = beta[n];
  }
  float s1[2][4], s2[2][4];
  #pragma unroll
  for (int mi = 0; mi < 2; ++mi)
    #pragma unroll
    for (int r = 0; r < 4; ++r) { s1[mi][r] = 0.f; s2[mi][r] = 0.f; }
  #pragma unroll
  for (int mi = 0; mi < 2; ++mi)
    #pragma unroll
    for (int ni = 0; ni < 4; ++ni)
      #pragma unroll
      for (int r = 0; r < 4; ++r) {
        int row = m0 + mi * 16 + g4 * 4 + r;
        int col = wn0 + ni * 16 + l15;
        float v = acc[mi][ni][r] + bv[ni] + bf2f(R[(size_t)row * 256 + swz(col, row & 7)]);
        acc[mi][ni][r] = v;
        s1[mi][r] += v;
        s2[mi][r] += v * v;
      }
  #pragma unroll
  for (int mi = 0; mi < 2; ++mi)
    #pragma unroll
    for (int r = 0; r < 4; ++r) {
      #pragma unroll
      for (int d = 1; d < 16; d <<= 1) {
        s1[mi][r] += __shfl_xor(s1[mi][r], d);
        s2[mi][r] += __shfl_xor(s2[mi][r], d);
      }
    }
  if (l15 == 0) {
    #pragma unroll
    for (int mi = 0; mi < 2; ++mi)
      #pragma unroll
      for (int r = 0; r < 4; ++r) {
        int rl = mi * 16 + g4 * 4 + r;
        red[w][rl][0] = s1[mi][r];
        red[w][rl][1] = s2[mi][r];
      }
  }
  __syncthreads();     // also guards Bsw reuse below (all K-loop reads done)
  float* Tr = (float*)Bsw;
  #pragma unroll
  for (int mi = 0; mi < 2; ++mi)
    #pragma unroll
    for (int r = 0; r < 4; ++r) {
      int rl = mi * 16 + g4 * 4 + r;
      float t1 = red[0][rl][0] + red[1][rl][0] + red[2][rl][0] + red[3][rl][0];
      float t2 = red[0][rl][1] + red[1][rl][1] + red[2][rl][1] + red[3][rl][1];
      float mu = t1 * (1.0f / 256.0f);
      float var = t2 * (1.0f / 256.0f) - mu * mu;
      float rstd = rsqrtf(var + 1e-5f);
      int row = m0 + rl;
      #pragma unroll
      for (int ni = 0; ni < 4; ++ni) {
        int col = wn0 + ni * 16 + l15;
        float res = (acc[mi][ni][r] - mu) * rstd * gv[ni] + bev[ni];
        if (!TRANS_OUT) {
          outb[(size_t)row * 256 + swz(col, row & 7)] = f2bf(res);
        } else {
          Tr[rl * 256 + col] = res;
        }
      }
    }
  if (TRANS_OUT) {
    __syncthreads();
    int b = m0 >> 10, sq0 = m0 & 1023, c = tid;
    float* dst = out + ((size_t)b << 18) + ((size_t)c << 10) + sq0;
    #pragma unroll
    for (int st = 0; st < 8; ++st) {
      float4 v;
      v.x = Tr[(st * 4 + 0) * 256 + c];
      v.y = Tr[(st * 4 + 1) * 256 + c];
      v.z = Tr[(st * 4 + 2) * 256 + c];
      v.w = Tr[(st * 4 + 3) * 256 + c];
      *(float4*)(dst + st * 4) = v;
    }
  }
}

// -------- 3. MFMA flash attention: 64 q-rows/block, shfl-based P redistribution --------
// K LDS: [32 r2][64 ushorts] view, 3-bit XOR slot swizzle (conflict-free b128 reads)
__global__ __launch_bounds__(256) void attn_mfma_kernel(
    const ushort* __restrict__ qkv, const ushort* __restrict__ vtg,
    ushort* __restrict__ att)
{
  __shared__ ushort Ks[2][64 * 32];
  __shared__ ushort Vt[2][32 * 64];
  const int tid = threadIdx.x, lane = tid & 63, w = tid >> 6;
  const int l15 = lane & 15, g = lane >> 4;
  const int qt = blockIdx.x, h = blockIdx.y, b = blockIdx.z;
  const size_t base = (size_t)b * SEQ * 768;
  const int q0 = qt * 64;
  const int bh = b * 8 + h;
  const float sc = 0.25507964954389985f;   // (1/sqrt(32)) * log2(e)

  // Q fragment: wave w owns q rows q0 + w*16 + l15
  bf16x8 qf = *(const bf16x8*)&qkv[base + (size_t)(q0 + w * 16 + l15) * 768 + h * 32 + g * 8];

  // K staging lane map ([32][64]-view, slot' = slot ^ (r2&7)):
  const int kr2l  = lane >> 3;                    // local r2 (0..7)
  const int kslot = (lane & 7) ^ kr2l;            // un-swizzled slot
  const int krow  = 2 * kr2l + (kslot >> 2);      // original K row within wave's 16
  const int kdoff = (kslot & 3) * 8;              // d-offset
  {
    gld_lds16(qkv + base + (size_t)(w * 16 + krow) * 768 + 256 + h * 32 + kdoff,
              &Ks[0][w * 512]);
    gld_lds16(vtg + ((size_t)bh * 32 + w * 8 + (lane >> 3)) * 1024 + (lane & 7) * 8,
              &Vt[0][w * 8 * 64]);
  }
  __syncthreads();

  float m_ = -1e30f, l_ = 0.f;
  f32x4 o[2];
  o[0] = (f32x4){0.f, 0.f, 0.f, 0.f};
  o[1] = (f32x4){0.f, 0.f, 0.f, 0.f};
  const f32x4 zero = (f32x4){0.f, 0.f, 0.f, 0.f};

  // P-redistribution shuffle sources (verified mapping)
  const int srcA = l15 + (((2 * g) & 3) << 4);
  const int srcB = l15 + (((2 * g + 1) & 3) << 4);
  const bool gh = (g & 2) != 0;

  int cur = 0;
  for (int t = 0; t < 16; ++t) {
    if (t < 15) {                          // prefetch next K/V tile
      int nkv = t * 64 + 64;
      gld_lds16(qkv + base + (size_t)(nkv + w * 16 + krow) * 768 + 256 + h * 32 + kdoff,
                &Ks[cur ^ 1][w * 512]);
      gld_lds16(vtg + ((size_t)bh * 32 + w * 8 + (lane >> 3)) * 1024 + nkv + (lane & 7) * 8,
                &Vt[cur ^ 1][w * 8 * 64]);
    }
    // S^T = K . Q^T : lane owns q = l15, t = ti*16 + g*4 + r
    bf16x8 kf[4];
    #pragma unroll
    for (int ti = 0; ti < 4; ++ti) {
      int r2   = ti * 8 + (l15 >> 1);
      int slot = (((l15 & 1) * 4 + g)) ^ (l15 >> 1);
      kf[ti] = *(const bf16x8*)&Ks[cur][r2 * 64 + slot * 8];
    }
    f32x4 s[4];
    __builtin_amdgcn_s_setprio(1);
    #pragma unroll
    for (int ti = 0; ti < 4; ++ti)
      s[ti] = __builtin_amdgcn_mfma_f32_16x16x32_bf16(kf[ti], qf, zero, 0, 0, 0);
    __builtin_amdgcn_s_setprio(0);

    // online softmax (q = l15); P stays in registers
    {
      float mx = s[0][0];
      #pragma unroll
      for (int ti = 0; ti < 4; ++ti)
        #pragma unroll
        for (int r = 0; r < 4; ++r) if (ti + r) mx = fmaxf(mx, s[ti][r]);
      mx = fmaxf(mx, __shfl_xor(mx, 16));
      mx = fmaxf(mx, __shfl_xor(mx, 32));
      if (!__all(mx <= m_ + 31.36f)) {     // defer-max: 8/sc raw-score units
        float mnew = fmaxf(m_, mx);
        float corr = exp2f((m_ - mnew) * sc);
        l_ *= corr;
        #pragma unroll
        for (int r = 0; r < 4; ++r) {
          float cr = __shfl(corr, g * 4 + r);
          o[0][r] *= cr; o[1][r] *= cr;
        }
        m_ = mnew;
      }
      float rs = 0.f;
      #pragma unroll
      for (int ti = 0; ti < 4; ++ti)
        #pragma unroll
        for (int r = 0; r < 4; ++r) {
          float p = exp2f((s[ti][r] - m_) * sc);
          s[ti][r] = p;
          rs += p;
        }
      rs += __shfl_xor(rs, 16);
      rs += __shfl_xor(rs, 32);
      l_ += rs;
    }

    // pack P -> bf16 dword pairs (v_cvt_pk_bf16_f32)
    unsigned pklo[4], pkhi[4];
    #pragma unroll
    for (int ti = 0; ti < 4; ++ti) {
      asm("v_cvt_pk_bf16_f32 %0, %1, %2" : "=v"(pklo[ti]) : "v"(s[ti][0]), "v"(s[ti][1]));
      asm("v_cvt_pk_bf16_f32 %0, %1, %2" : "=v"(pkhi[ti]) : "v"(s[ti][2]), "v"(s[ti][3]));
    }
    // redistribute to PV A-fragments: lane (l15,g) needs t = ks*32 + g*8 + j
    bf16x8 pa[2];
    #pragma unroll
    for (int ks = 0; ks < 2; ++ks) {
      unsigned a0 = (unsigned)__shfl((int)pklo[2 * ks],     srcA);
      unsigned b0 = (unsigned)__shfl((int)pklo[2 * ks + 1], srcA);
      unsigned a1 = (unsigned)__shfl((int)pkhi[2 * ks],     srcA);
      unsigned b1 = (unsigned)__shfl((int)pkhi[2 * ks + 1], srcA);
      unsigned a2 = (unsigned)__shfl((int)pklo[2 * ks],     srcB);
      unsigned b2 = (unsigned)__shfl((int)pklo[2 * ks + 1], srcB);
      unsigned a3 = (unsigned)__shfl((int)pkhi[2 * ks],     srcB);
      unsigned b3 = (unsigned)__shfl((int)pkhi[2 * ks + 1], srcB);
      uint4 pw;
      pw.x = gh ? b0 : a0;
      pw.y = gh ? b1 : a1;
      pw.z = gh ? b2 : a2;
      pw.w = gh ? b3 : a3;
      pa[ks] = *(bf16x8*)&pw;
    }

    // O += P . V
    bf16x8 vb[2][2];
    #pragma unroll
    for (int ks = 0; ks < 2; ++ks)
      #pragma unroll
      for (int di = 0; di < 2; ++di) {
        int d = di * 16 + l15;
        vb[ks][di] = *(const bf16x8*)&Vt[cur][d * 64 + (((ks * 4 + g) ^ (d & 7)) * 8)];
      }
    __builtin_amdgcn_s_setprio(1);
    #pragma unroll
    for (int di = 0; di < 2; ++di)
      #pragma unroll
      for (int ks = 0; ks < 2; ++ks)
        o[di] = __builtin_amdgcn_mfma_f32_16x16x32_bf16(pa[ks], vb[ks][di], o[di], 0, 0, 0);
    __builtin_amdgcn_s_setprio(0);
    __syncthreads();
    cur ^= 1;
  }

  // normalized store, swizzled bf16 [8192][256]
  #pragma unroll
  for (int r = 0; r < 4; ++r) {
    float lr = __shfl(l_, g * 4 + r);
    float inv = 1.0f / lr;
    size_t row = (size_t)b * SEQ + q0 + w * 16 + g * 4 + r;
    int rw7 = (g * 4 + r) & 7;
    #pragma unroll
    for (int di = 0; di < 2; ++di) {
      int col = h * 32 + di * 16 + l15;
      att[row * 256 + swz(col, rw7)] = f2bf(o[di][r] * inv);
    }
  }
}

extern "C" void kernel_launch(void* const* d_in, const int* in_sizes, int n_in,
                              void* d_out, int out_size, void* d_ws, size_t ws_size,
                              hipStream_t stream)
{
  const float* x    = (const float*)d_in[0];
  const float* y    = (const float*)d_in[1];
  const float* Wqkv = (const float*)d_in[3];
  const float* bqkv = (const float*)d_in[4];
  const float* Wo   = (const float*)d_in[5];
  const float* bo   = (const float*)d_in[6];
  const float* W1   = (const float*)d_in[7];
  const float* b1   = (const float*)d_in[8];
  const float* W2   = (const float*)d_in[9];
  const float* b2   = (const float*)d_in[10];
  const float* g1   = (const float*)d_in[11];
  const float* be1  = (const float*)d_in[12];
  const float* g2   = (const float*)d_in[13];
  const float* be2  = (const float*)d_in[14];

  float* ws = (float*)d_ws;
  ushort* f_bf   = (ushort*)(ws);                 // [0, 1M) floats: swizzled bf16
  ushort* qkv_bf = (ushort*)(ws + 1048576);       // [1M, 4M): Q,K linear (V cols unused)
  ushort* vt_g   = (ushort*)(ws + 4194304);       // [4M, 5M): vt[bh][32][1024] swizzled
  ushort* att_bf = (ushort*)(ws + 5242880);       // [5M, 6M) swizzled
  ushort* f1_bf  = (ushort*)(ws + 6291456);       // [6M, 7M) swizzled
  ushort* h_bf   = (ushort*)(ws + 7340032);       // [7M, 11M) swizzled
  float*  pos    = ws + 11534336;                 // [11M, 11.25M)
  ushort* wq_bf  = (ushort*)(ws + 12582912);
  ushort* wo_bf  = wq_bf + 196608;
  ushort* w1_bf  = wo_bf + 65536;
  ushort* w2_bf  = w1_bf + 262144;

  prep_kernel<<<1024, 256, 0, stream>>>(Wqkv, Wo, W1, W2, wq_bf, wo_bf, w1_bf, w2_bf, pos);
  build_f_kernel<<<512, 256, 0, stream>>>(x, y, pos, f_bf);
  gemm_mfma_kernel<64, 3, 0><<<dim3(6, 128), 256, 0, stream>>>(
      f_bf, wq_bf, bqkv, qkv_bf, vt_g, NROWS, 768, 256);
  attn_mfma_kernel<<<dim3(16, 8, 8), 256, 0, stream>>>(qkv_bf, vt_g, att_bf);
  gemm_ln_kernel<0><<<256, 256, 0, stream>>>(att_bf, wo_bf, bo, f_bf, g1, be1, nullptr, f1_bf, 256);
  gemm_mfma_kernel<128, 2, 1><<<dim3(8, 64), 256, 0, stream>>>(
      f1_bf, w1_bf, b1, h_bf, nullptr, NROWS, 1024, 256);
  gemm_ln_kernel<1><<<256, 256, 0, stream>>>(h_bf, w2_bf, b2, f1_bf, g2, be2, (float*)d_out, nullptr, 1024);
}